// Round 3
// baseline (414.745 us; speedup 1.0000x reference)
//
#include <hip/hip_runtime.h>
#include <stdint.h>
#include <math.h>

// Problem constants (B,L,H,D fixed by setup_inputs)
#define Bn 4
#define Ln 2048
#define Hn 8
#define Dn 64
#define BHn (Bn*Hn)
#define NTOP 40   // FACTOR * ceil(log(2048)) = 5*8
#define SK   40
#define NSAMP (Ln*SK)        // 81920

// ---------------- Threefry-2x32 (exact JAX replication) ----------------
__host__ __device__ inline uint32_t rotl32(uint32_t x, int r) {
  return (x << r) | (x >> (32 - r));
}

__host__ __device__ inline void tf2x32(uint32_t k0, uint32_t k1,
                                       uint32_t& x0, uint32_t& x1) {
  const uint32_t ks2 = k0 ^ k1 ^ 0x1BD11BDAu;
  const int RA[4] = {13, 15, 26, 6};
  const int RB[4] = {17, 29, 16, 24};
  x0 += k0; x1 += k1;
  for (int i = 0; i < 4; i++) { x0 += x1; x1 = rotl32(x1, RA[i]); x1 ^= x0; }
  x0 += k1;  x1 += ks2 + 1u;
  for (int i = 0; i < 4; i++) { x0 += x1; x1 = rotl32(x1, RB[i]); x1 ^= x0; }
  x0 += ks2; x1 += k0 + 2u;
  for (int i = 0; i < 4; i++) { x0 += x1; x1 = rotl32(x1, RA[i]); x1 ^= x0; }
  x0 += k0;  x1 += k1 + 3u;
  for (int i = 0; i < 4; i++) { x0 += x1; x1 = rotl32(x1, RB[i]); x1 ^= x0; }
  x0 += k1;  x1 += ks2 + 4u;
  for (int i = 0; i < 4; i++) { x0 += x1; x1 = rotl32(x1, RA[i]); x1 ^= x0; }
  x0 += ks2; x1 += k0 + 5u;
}

// jax_threefry_partitionable=True: elem n -> ctr (0, n); draw = out0 ^ out1
__device__ inline int draw2048(uint32_t k0, uint32_t k1, uint32_t n) {
  uint32_t a = 0u, b = n;
  tf2x32(k0, k1, a, b);
  return (int)((a ^ b) & (Ln - 1));
}

// ---------------- DPP 16-lane sum reduce (VALU pipe, zero DS ops) ----------------
template<int CTRL>
__device__ __forceinline__ float dpp_add(float x) {
  int y = __builtin_amdgcn_update_dpp(0, __float_as_int(x), CTRL, 0xF, 0xF, true);
  return x + __int_as_float(y);
}
__device__ __forceinline__ float red16(float d) {
  d = dpp_add<0xB1>(d);   // quad_perm [1,0,3,2]  (xor 1)
  d = dpp_add<0x4E>(d);   // quad_perm [2,3,0,1]  (xor 2)
  d = dpp_add<0x141>(d);  // row_half_mirror      (pairs across 8-halves)
  d = dpp_add<0x140>(d);  // row_mirror           (pairs across 16-row)
  return d;
}

// ---------------- M = max_s(QK_s) - sum_s(QK_s)/L ----------------
// v3 (validated R1/R2, time == v2): quarter-wave-cooperative coalesced gather;
// sample-index table in LDS read as int4; 16-lane dot reduce via DPP.
__global__ __launch_bounds__(256) void compute_M(const float* __restrict__ Q,
                                                 const float* __restrict__ K,
                                                 float* __restrict__ M,
                                                 uint32_t k0, uint32_t k1) {
  int xcd = blockIdx.x & 7;
  int idx = blockIdx.x >> 3;          // 0..511
  int bh  = (idx & 3) * 8 + xcd;      // {xcd, xcd+8, xcd+16, xcd+24}
  int seg = idx >> 2;                 // 0..127
  int tid = threadIdx.x;
  int qw  = tid >> 4;                 // query slot in wg: 0..15
  int j   = tid & 15;                 // lane within quarter-wave
  int i   = seg * 16 + qw;            // query index

  __shared__ alignas(16) int sidx[16][40];   // 2.5 KB sample-index table

  uint32_t n0 = (uint32_t)(i * SK);
  sidx[qw][j]      = draw2048(k0, k1, n0 + j);
  sidx[qw][16 + j] = draw2048(k0, k1, n0 + 16 + j);
  if (j < 8) sidx[qw][32 + j] = draw2048(k0, k1, n0 + 32 + j);

  const float* Qb = Q + ((size_t)bh * Ln + i) * Dn;
  float4 qf = ((const float4*)Qb)[j];
  __syncthreads();

  // pull all 40 indices into registers up front (compile-time indexed -> VGPRs)
  int4 I[10];
#pragma unroll
  for (int t = 0; t < 10; t++) I[t] = *(const int4*)&sidx[qw][t * 4];

  const float* Kb = K + (size_t)bh * Ln * Dn;
  float mx = -INFINITY, sm = 0.f;
#pragma unroll
  for (int t = 0; t < 10; t++) {
    int ls[4] = {I[t].x, I[t].y, I[t].z, I[t].w};
#pragma unroll
    for (int c = 0; c < 4; c++) {
      float4 kf = ((const float4*)(Kb + (size_t)ls[c] * Dn))[j];
      float d = qf.x * kf.x + qf.y * kf.y + qf.z * kf.z + qf.w * kf.w;
      d = red16(d);                    // full 64-elem dot in every lane
      mx = fmaxf(mx, d);
      sm += d;
    }
  }
  if (j == 0)
    M[(size_t)bh * Ln + i] = mx - sm * (1.0f / (float)Ln);
}

// ---------------- top-40, fused: one wg (4 waves) per bh ----------------
__global__ __launch_bounds__(256) void topk_fused(const float* __restrict__ M,
                                                  int* __restrict__ Mtop) {
  int bh = blockIdx.x;
  int tid = threadIdx.x, lane = tid & 63, w = tid >> 6;
  __shared__ float cv[4][NTOP];
  __shared__ int   ci[4][NTOP];
  {
    float cur[8];
    const float* m = M + (size_t)bh * Ln + w * 512;
#pragma unroll
    for (int j = 0; j < 8; j++) cur[j] = m[lane + 64 * j];
    for (int k = 0; k < NTOP; ++k) {
      float bv = cur[0]; int bj = 0;
#pragma unroll
      for (int j = 1; j < 8; j++)
        if (cur[j] > bv) { bv = cur[j]; bj = j; }  // ties keep smaller j
      int bi = w * 512 + lane + 64 * bj;           // bh-local global index
#pragma unroll
      for (int off = 1; off < 64; off <<= 1) {
        float ov = __shfl_xor(bv, off, 64);
        int   oi = __shfl_xor(bi, off, 64);
        if (ov > bv || (ov == bv && oi < bi)) { bv = ov; bi = oi; }
      }
      if (lane == 0) { cv[w][k] = bv; ci[w][k] = bi; }
      int ll  = bi & 63;
      int jj = (bi - w * 512) >> 6;
      if (lane == ll) cur[jj] = -INFINITY;
    }
  }
  __syncthreads();
  if (w == 0) {
    float cur[3]; int gix[3];
#pragma unroll
    for (int j = 0; j < 3; j++) {
      int c = lane + 64 * j;
      if (c < 160) { cur[j] = cv[c / NTOP][c % NTOP]; gix[j] = ci[c / NTOP][c % NTOP]; }
      else         { cur[j] = -INFINITY; gix[j] = 0x7fffffff; }
    }
    for (int k = 0; k < NTOP; ++k) {
      float bv = cur[0]; int bg = gix[0];
#pragma unroll
      for (int j = 1; j < 3; j++)
        if (cur[j] > bv || (cur[j] == bv && gix[j] < bg)) { bv = cur[j]; bg = gix[j]; }
#pragma unroll
      for (int off = 1; off < 64; off <<= 1) {
        float ov = __shfl_xor(bv, off, 64);
        int   og = __shfl_xor(bg, off, 64);
        if (ov > bv || (ov == bv && og < bg)) { bv = ov; bg = og; }
      }
      if (lane == 0) Mtop[bh * NTOP + k] = bg;
#pragma unroll
      for (int j = 0; j < 3; j++)
        if (gix[j] == bg) cur[j] = -INFINITY;
    }
  }
}

// ---------------- context cumsum, phase 1: per-tile (64 l) sums ----------------
__global__ __launch_bounds__(256) void vsum_partial(const float* __restrict__ V,
                                                    float* __restrict__ partial) {
  int tile = blockIdx.x & 31;
  int bh   = blockIdx.x >> 5;
  int d = threadIdx.x & 63;
  int g = threadIdx.x >> 6;
  const float* Vb = V + (size_t)bh * Ln * Dn;
  int l0 = tile * 64 + g * 16;
  float s = 0.f;
  for (int j = 0; j < 16; j++) s += Vb[(size_t)(l0 + j) * Dn + d];
  __shared__ float red[4][64];
  red[g][d] = s;
  __syncthreads();
  if (g == 0)
    partial[((size_t)bh * 32 + tile) * 64 + d] =
        red[0][d] + red[1][d] + red[2][d] + red[3][d];
}

// ---------------- context cumsum, phase 2: prefix + cumsum + transposed write ----------------
__global__ __launch_bounds__(256) void context_write(const float* __restrict__ V,
                                                     const float* __restrict__ partial,
                                                     float* __restrict__ out) {
  int tile = blockIdx.x & 31;
  int bh   = blockIdx.x >> 5;
  int b = bh >> 3, h = bh & 7;
  int d = threadIdx.x & 63;
  int g = threadIdx.x >> 6;
  __shared__ float red[4][64];
  float p = 0.f;
  for (int t = g; t < tile; t += 4)
    p += partial[((size_t)bh * 32 + t) * 64 + d];
  red[g][d] = p;
  __syncthreads();
  float prefix = red[0][d] + red[1][d] + red[2][d] + red[3][d];
  __syncthreads();
  const float* Vb = V + (size_t)bh * Ln * Dn;
  int l0 = tile * 64 + g * 16;
  float vloc[16]; float s = 0.f;
  for (int j = 0; j < 16; j++) {
    vloc[j] = Vb[(size_t)(l0 + j) * Dn + d];
    s += vloc[j];
  }
  red[g][d] = s;
  __syncthreads();
  float running = prefix;
  for (int gg = 0; gg < g; gg++) running += red[gg][d];
  for (int j = 0; j < 16; j++) {
    int l = l0 + j;
    running += vloc[j];
    out[(((size_t)b * Ln + l) * Hn + h) * Dn + d] =
        0.5f * ((float)(l + 1) * vloc[j] + running);
  }
}

// ---------------- sparse attention over the 40 selected rows ----------------
// v4: EXACT R0-proven structure (streaming tt-loop pass 1, LDS qs/ks/vs,
// pure register accumulation, no DPP, no lane-resident fragments -- the
// R1/R2 cooperative-row design triggered a 177 MB scratch pathology in
// hipcc regardless of load depth and is abandoned). One change vs R0:
// 1024 threads/block (16 waves/CU instead of 8). R0's counters showed the
// latency/occupancy signature (HBM 6%, VALU 20%, occ 20.8% = the 25%
// ceiling of 1 block/CU x 8 waves): pass 1/3 load latency was exposed with
// only 2 waves/SIMD. 16 waves doubles latency hiding; per-thread in-flight
// load VGPRs HALVE vs R0 (kk[2][4]+qq[2][4]=64 vs 128), moving away from
// the spill cliff. All array indexing compile-time static.
#define UC 5
__global__ __launch_bounds__(1024) void sparse_attn(const float* __restrict__ Q,
                                                    const float* __restrict__ K,
                                                    const float* __restrict__ V,
                                                    const int* __restrict__ Mtop,
                                                    float* __restrict__ out) {
  int xcd  = blockIdx.x & 7;
  int rest = blockIdx.x >> 3;     // 0..31
  int chunk = rest & 7;
  int bh    = (rest >> 3) * 8 + xcd;
  int b = bh >> 3, h = bh & 7;
  __shared__ alignas(16) float sc[UC][Ln];           // 40 KB scores->probs
  __shared__ alignas(16) float qs[UC][Dn];
  __shared__ alignas(16) float ks[UC][Dn];
  __shared__ float vs[UC][Dn];
  __shared__ alignas(16) float redp[16][UC][64];     // 20 KB partial attn@V
  __shared__ int   rows_s[UC];
  __shared__ float inv_s[UC];
  const float* Qb = Q + (size_t)bh * Ln * Dn;
  const float* Kb = K + (size_t)bh * Ln * Dn;
  const float* Vb = V + (size_t)bh * Ln * Dn;
  int tid = threadIdx.x;

  if (tid < UC * 64) {
    int u = tid >> 6, d = tid & 63;
    int row = Mtop[bh * NTOP + chunk * UC + u];
    if (d == 0) rows_s[u] = row;
    qs[u][d] = Qb[(size_t)row * Dn + d];
    ks[u][d] = Kb[(size_t)row * Dn + d];
    vs[u][d] = Vb[(size_t)row * Dn + d];
  }
  __syncthreads();

  // pass 1: scores[u][l] = 0.0625*(Qsel[u].K[l] + Q[l].Ksel[u]), causal mask l>row
  float acc[UC][2];
#pragma unroll
  for (int u = 0; u < UC; u++)
#pragma unroll
    for (int j = 0; j < 2; j++) acc[u][j] = 0.f;

  for (int tt = 0; tt < 4; tt++) {
    float4 kk[2][4], qq[2][4];    // [j][ts] -- 16 loads issued before use
#pragma unroll
    for (int j = 0; j < 2; j++) {
      int l = tid + j * 1024;
      const float4* kp = (const float4*)(Kb + (size_t)l * Dn) + tt * 4;
      const float4* qp = (const float4*)(Qb + (size_t)l * Dn) + tt * 4;
#pragma unroll
      for (int ts = 0; ts < 4; ts++) { kk[j][ts] = kp[ts]; qq[j][ts] = qp[ts]; }
    }
#pragma unroll
    for (int ts = 0; ts < 4; ts++) {
      int t = tt * 4 + ts;
#pragma unroll
      for (int u = 0; u < UC; u++) {
        float4 q4 = *(const float4*)(&qs[u][t * 4]);
        float4 k4 = *(const float4*)(&ks[u][t * 4]);
#pragma unroll
        for (int j = 0; j < 2; j++) {
          acc[u][j] += q4.x * kk[j][ts].x + q4.y * kk[j][ts].y
                     + q4.z * kk[j][ts].z + q4.w * kk[j][ts].w
                     + k4.x * qq[j][ts].x + k4.y * qq[j][ts].y
                     + k4.z * qq[j][ts].z + k4.w * qq[j][ts].w;
        }
      }
    }
  }
#pragma unroll
  for (int u = 0; u < UC; u++) {
    int row = rows_s[u];
#pragma unroll
    for (int j = 0; j < 2; j++) {
      int l = tid + j * 1024;
      sc[u][l] = (l > row) ? -1e9f : acc[u][j] * 0.0625f;
    }
  }
  __syncthreads();

  // pass 2: softmax per u; wave w handles u=w (waves 0..4)
  int w = tid >> 6, lane = tid & 63;
  if (w < UC) {
    float mx = -INFINITY;
    for (int kq = 0; kq < 32; kq++) mx = fmaxf(mx, sc[w][lane + 64 * kq]);
    for (int off = 32; off; off >>= 1) mx = fmaxf(mx, __shfl_xor(mx, off, 64));
    float sum = 0.f;
    for (int kq = 0; kq < 32; kq++) {
      float e = __expf(sc[w][lane + 64 * kq] - mx);
      sc[w][lane + 64 * kq] = e;
      sum += e;
    }
    for (int off = 32; off; off >>= 1) sum += __shfl_xor(sum, off, 64);
    if (lane == 0) inv_s[w] = 1.0f / sum;
  }
  __syncthreads();

  // pass 3: attn @ V ; wave w (0..15) owns l in [w*128, w*128+128) for ALL 5 u.
  {
    int quad = lane & 15, lr = lane >> 4;
    int l0w = w * 128;
    const float4* V4 = (const float4*)Vb;
    float4 a[UC];
#pragma unroll
    for (int u = 0; u < UC; u++) a[u] = make_float4(0.f, 0.f, 0.f, 0.f);
    for (int it4 = 0; it4 < 8; it4++) {
      int lb = l0w + lr + it4 * 16;
      float4 v0 = V4[(size_t)(lb)      * 16 + quad];
      float4 v1 = V4[(size_t)(lb + 4)  * 16 + quad];
      float4 v2 = V4[(size_t)(lb + 8)  * 16 + quad];
      float4 v3 = V4[(size_t)(lb + 12) * 16 + quad];
#pragma unroll
      for (int u = 0; u < UC; u++) {
        float s0 = sc[u][lb], s1 = sc[u][lb + 4], s2 = sc[u][lb + 8], s3 = sc[u][lb + 12];
        a[u].x += s0 * v0.x + s1 * v1.x + s2 * v2.x + s3 * v3.x;
        a[u].y += s0 * v0.y + s1 * v1.y + s2 * v2.y + s3 * v3.y;
        a[u].z += s0 * v0.z + s1 * v1.z + s2 * v2.z + s3 * v3.z;
        a[u].w += s0 * v0.w + s1 * v1.w + s2 * v2.w + s3 * v3.w;
      }
    }
#pragma unroll
    for (int u = 0; u < UC; u++) {
#pragma unroll
      for (int off = 16; off < 64; off <<= 1) {
        a[u].x += __shfl_xor(a[u].x, off, 64);
        a[u].y += __shfl_xor(a[u].y, off, 64);
        a[u].z += __shfl_xor(a[u].z, off, 64);
        a[u].w += __shfl_xor(a[u].w, off, 64);
      }
      if (lr == 0) *(float4*)(&redp[w][u][quad * 4]) = a[u];
    }
  }
  __syncthreads();

  if (w < UC) {
    float r = 0.f;
#pragma unroll
    for (int g = 0; g < 16; g++) r += redp[g][w][lane];
    float outv = 0.5f * (vs[w][lane] + r * inv_s[w]);
    int row = rows_s[w];
    out[(((size_t)b * Ln + row) * Hn + h) * Dn + lane] = outv;
  }
}

extern "C" void kernel_launch(void* const* d_in, const int* in_sizes, int n_in,
                              void* d_out, int out_size, void* d_ws, size_t ws_size,
                              hipStream_t stream) {
  const float* Q = (const float*)d_in[0];  // (B,L,H,D) flat == (B,H,L,D) reshape
  const float* K = (const float*)d_in[1];
  const float* V = (const float*)d_in[2];
  float* out = (float*)d_out;
  char* ws = (char*)d_ws;

  float* M       = (float*)(ws + NSAMP * 4);                       // 256 KB
  int*   Mtop    = (int*)(ws + NSAMP * 4 + BHn * Ln * 4);          // 5 KB
  float* partial = (float*)(ws + NSAMP * 4 + BHn * Ln * 4 + BHn * NTOP * 4); // 256 KB

  // Partitionable threefry split of key(42) = (0,42): k2 = tf(key, ctr=(0,1)).
  uint32_t s0 = 0u, s1 = 1u;
  tf2x32(0u, 42u, s0, s1);

  compute_M<<<4096, 256, 0, stream>>>(Q, K, M, s0, s1);
  topk_fused<<<BHn, 256, 0, stream>>>(M, Mtop);
  vsum_partial<<<BHn * 32, 256, 0, stream>>>(V, partial);
  context_write<<<BHn * 32, 256, 0, stream>>>(V, partial, out);
  sparse_attn<<<BHn * 8, 1024, 0, stream>>>(Q, K, V, Mtop, out);
}

// Round 5
// 216.494 us; speedup vs baseline: 1.9157x; 1.9157x over previous
//
#include <hip/hip_runtime.h>
#include <stdint.h>
#include <math.h>

// Problem constants (B,L,H,D fixed by setup_inputs)
#define Bn 4
#define Ln 2048
#define Hn 8
#define Dn 64
#define BHn (Bn*Hn)
#define NTOP 40   // FACTOR * ceil(log(2048)) = 5*8
#define SK   40
#define NSAMP (Ln*SK)        // 81920

// ---------------- Threefry-2x32 (exact JAX replication) ----------------
__host__ __device__ inline uint32_t rotl32(uint32_t x, int r) {
  return (x << r) | (x >> (32 - r));
}

__host__ __device__ inline void tf2x32(uint32_t k0, uint32_t k1,
                                       uint32_t& x0, uint32_t& x1) {
  const uint32_t ks2 = k0 ^ k1 ^ 0x1BD11BDAu;
  const int RA[4] = {13, 15, 26, 6};
  const int RB[4] = {17, 29, 16, 24};
  x0 += k0; x1 += k1;
  for (int i = 0; i < 4; i++) { x0 += x1; x1 = rotl32(x1, RA[i]); x1 ^= x0; }
  x0 += k1;  x1 += ks2 + 1u;
  for (int i = 0; i < 4; i++) { x0 += x1; x1 = rotl32(x1, RB[i]); x1 ^= x0; }
  x0 += ks2; x1 += k0 + 2u;
  for (int i = 0; i < 4; i++) { x0 += x1; x1 = rotl32(x1, RA[i]); x1 ^= x0; }
  x0 += k0;  x1 += k1 + 3u;
  for (int i = 0; i < 4; i++) { x0 += x1; x1 = rotl32(x1, RB[i]); x1 ^= x0; }
  x0 += k1;  x1 += ks2 + 4u;
  for (int i = 0; i < 4; i++) { x0 += x1; x1 = rotl32(x1, RA[i]); x1 ^= x0; }
  x0 += ks2; x1 += k0 + 5u;
}

// jax_threefry_partitionable=True: elem n -> ctr (0, n); draw = out0 ^ out1
__device__ inline int draw2048(uint32_t k0, uint32_t k1, uint32_t n) {
  uint32_t a = 0u, b = n;
  tf2x32(k0, k1, a, b);
  return (int)((a ^ b) & (Ln - 1));
}

// ---------------- DPP 16-lane sum reduce (VALU pipe, zero DS ops) ----------------
template<int CTRL>
__device__ __forceinline__ float dpp_add(float x) {
  int y = __builtin_amdgcn_update_dpp(0, __float_as_int(x), CTRL, 0xF, 0xF, true);
  return x + __int_as_float(y);
}
__device__ __forceinline__ float red16(float d) {
  d = dpp_add<0xB1>(d);   // quad_perm [1,0,3,2]  (xor 1)
  d = dpp_add<0x4E>(d);   // quad_perm [2,3,0,1]  (xor 2)
  d = dpp_add<0x141>(d);  // row_half_mirror      (pairs across 8-halves)
  d = dpp_add<0x140>(d);  // row_mirror           (pairs across 16-row)
  return d;
}

// ---------------- fused launch 1: vsum_partial (blocks 0..1023) +
//                  compute_M (blocks 1024..5119) ----------------
// The two independent dependency chains {M-scoring on Q,K} and {V-cumsum}
// previously serialized across launches. compute_M is a latency-bound gather
// (HBM 4%, occ 44%); vsum is pure BW -- ideal co-tenants on one grid.
// Offset 1024 === 0 mod 8 keeps compute_M's XCD swizzle intact.
__global__ __launch_bounds__(256) void fused_m_vsum(const float* __restrict__ Q,
                                                    const float* __restrict__ K,
                                                    const float* __restrict__ V,
                                                    float* __restrict__ M,
                                                    float* __restrict__ partial,
                                                    uint32_t k0, uint32_t k1) {
  __shared__ alignas(16) int sidx[16][40];   // compute_M path (2.5 KB)
  __shared__ float red[4][64];               // vsum path (1 KB)

  if (blockIdx.x < 1024) {
    // ---- vsum_partial: per-tile (64 l) V sums ----
    int bid  = blockIdx.x;
    int tile = bid & 31;
    int bh   = bid >> 5;
    int d = threadIdx.x & 63;
    int g = threadIdx.x >> 6;
    const float* Vb = V + (size_t)bh * Ln * Dn;
    int l0 = tile * 64 + g * 16;
    float s = 0.f;
    for (int j = 0; j < 16; j++) s += Vb[(size_t)(l0 + j) * Dn + d];
    red[g][d] = s;
    __syncthreads();
    if (g == 0)
      partial[((size_t)bh * 32 + tile) * 64 + d] =
          red[0][d] + red[1][d] + red[2][d] + red[3][d];
    return;
  }

  // ---- compute_M v3 (validated R1-R3): quarter-wave-cooperative gather,
  // LDS sample-index table read as int4, DPP dot reduce ----
  int cmb = blockIdx.x - 1024;        // 0..4095; 1024%8==0 keeps xcd mapping
  int xcd = cmb & 7;
  int idx = cmb >> 3;                 // 0..511
  int bh  = (idx & 3) * 8 + xcd;      // {xcd, xcd+8, xcd+16, xcd+24}
  int seg = idx >> 2;                 // 0..127
  int tid = threadIdx.x;
  int qw  = tid >> 4;                 // query slot in wg: 0..15
  int j   = tid & 15;                 // lane within quarter-wave
  int i   = seg * 16 + qw;            // query index

  uint32_t n0 = (uint32_t)(i * SK);
  sidx[qw][j]      = draw2048(k0, k1, n0 + j);
  sidx[qw][16 + j] = draw2048(k0, k1, n0 + 16 + j);
  if (j < 8) sidx[qw][32 + j] = draw2048(k0, k1, n0 + 32 + j);

  const float* Qb = Q + ((size_t)bh * Ln + i) * Dn;
  float4 qf = ((const float4*)Qb)[j];
  __syncthreads();

  // pull all 40 indices into registers up front (compile-time indexed -> VGPRs)
  int4 I[10];
#pragma unroll
  for (int t = 0; t < 10; t++) I[t] = *(const int4*)&sidx[qw][t * 4];

  const float* Kb = K + (size_t)bh * Ln * Dn;
  float mx = -INFINITY, sm = 0.f;
#pragma unroll
  for (int t = 0; t < 10; t++) {
    int ls[4] = {I[t].x, I[t].y, I[t].z, I[t].w};
#pragma unroll
    for (int c = 0; c < 4; c++) {
      float4 kf = ((const float4*)(Kb + (size_t)ls[c] * Dn))[j];
      float d = qf.x * kf.x + qf.y * kf.y + qf.z * kf.z + qf.w * kf.w;
      d = red16(d);                    // full 64-elem dot in every lane
      mx = fmaxf(mx, d);
      sm += d;
    }
  }
  if (j == 0)
    M[(size_t)bh * Ln + i] = mx - sm * (1.0f / (float)Ln);
}

// ---------------- fused launch 2: topk (blocks 0..31) +
//                  context_write (blocks 32..1055) ----------------
// topk occupies only 32 of 256 CUs and is latency-chained; context_write's
// 32 MB stream fills the other 224. Offset 32 === 0 mod 32 keeps the
// tile/bh decomposition intact.
__global__ __launch_bounds__(256) void fused_topk_ctx(const float* __restrict__ M,
                                                      int* __restrict__ Mtop,
                                                      const float* __restrict__ V,
                                                      const float* __restrict__ partial,
                                                      float* __restrict__ out) {
  __shared__ float cv[4][NTOP];
  __shared__ int   ci[4][NTOP];
  __shared__ float red[4][64];

  if (blockIdx.x < 32) {
    // ---- top-40 (proven): wave w exact top-40 of its 512-seg, wave 0 merges ----
    int bh = blockIdx.x;
    int tid = threadIdx.x, lane = tid & 63, w = tid >> 6;
    {
      float cur[8];
      const float* m = M + (size_t)bh * Ln + w * 512;
#pragma unroll
      for (int j = 0; j < 8; j++) cur[j] = m[lane + 64 * j];
      for (int k = 0; k < NTOP; ++k) {
        float bv = cur[0]; int bj = 0;
#pragma unroll
        for (int j = 1; j < 8; j++)
          if (cur[j] > bv) { bv = cur[j]; bj = j; }  // ties keep smaller j
        int bi = w * 512 + lane + 64 * bj;           // bh-local global index
#pragma unroll
        for (int off = 1; off < 64; off <<= 1) {
          float ov = __shfl_xor(bv, off, 64);
          int   oi = __shfl_xor(bi, off, 64);
          if (ov > bv || (ov == bv && oi < bi)) { bv = ov; bi = oi; }
        }
        if (lane == 0) { cv[w][k] = bv; ci[w][k] = bi; }
        int ll  = bi & 63;
        int jj = (bi - w * 512) >> 6;
        if (lane == ll) cur[jj] = -INFINITY;
      }
    }
    __syncthreads();
    if (w == 0) {
      float cur[3]; int gix[3];
#pragma unroll
      for (int j = 0; j < 3; j++) {
        int c = lane + 64 * j;
        if (c < 160) { cur[j] = cv[c / NTOP][c % NTOP]; gix[j] = ci[c / NTOP][c % NTOP]; }
        else         { cur[j] = -INFINITY; gix[j] = 0x7fffffff; }
      }
      for (int k = 0; k < NTOP; ++k) {
        float bv = cur[0]; int bg = gix[0];
#pragma unroll
        for (int j = 1; j < 3; j++)
          if (cur[j] > bv || (cur[j] == bv && gix[j] < bg)) { bv = cur[j]; bg = gix[j]; }
#pragma unroll
        for (int off = 1; off < 64; off <<= 1) {
          float ov = __shfl_xor(bv, off, 64);
          int   og = __shfl_xor(bg, off, 64);
          if (ov > bv || (ov == bv && og < bg)) { bv = ov; bg = og; }
        }
        if (lane == 0) Mtop[bh * NTOP + k] = bg;
#pragma unroll
        for (int j = 0; j < 3; j++)
          if (gix[j] == bg) cur[j] = -INFINITY;
      }
    }
    return;
  }

  // ---- context_write: prefix + cumsum + transposed write ----
  int bid  = blockIdx.x - 32;
  int tile = bid & 31;
  int bh   = bid >> 5;
  int b = bh >> 3, h = bh & 7;
  int d = threadIdx.x & 63;
  int g = threadIdx.x >> 6;
  float p = 0.f;
  for (int t = g; t < tile; t += 4)
    p += partial[((size_t)bh * 32 + t) * 64 + d];
  red[g][d] = p;
  __syncthreads();
  float prefix = red[0][d] + red[1][d] + red[2][d] + red[3][d];
  __syncthreads();
  const float* Vb = V + (size_t)bh * Ln * Dn;
  int l0 = tile * 64 + g * 16;
  float vloc[16]; float s = 0.f;
  for (int j = 0; j < 16; j++) {
    vloc[j] = Vb[(size_t)(l0 + j) * Dn + d];
    s += vloc[j];
  }
  red[g][d] = s;
  __syncthreads();
  float running = prefix;
  for (int gg = 0; gg < g; gg++) running += red[gg][d];
  for (int j = 0; j < 16; j++) {
    int l = l0 + j;
    running += vloc[j];
    out[(((size_t)b * Ln + l) * Hn + h) * Dn + d] =
        0.5f * ((float)(l + 1) * vloc[j] + running);
  }
}

// ---------------- sparse attention over the 40 selected rows ----------------
// EXACT R0-proven version (58 us, WRITE 2.9 MB, no scratch). R1-R3 all
// perturbed this structure (lane-resident fragments / 1024-thread blocks)
// and each tripped a hipcc scratch-spill cliff (177-310 MB WRITE_SIZE).
// The 512-thread / 128-VGPR balance is load-bearing; do not restructure.
#define UC 5
__global__ __launch_bounds__(512, 2) void sparse_attn(const float* __restrict__ Q,
                                                      const float* __restrict__ K,
                                                      const float* __restrict__ V,
                                                      const int* __restrict__ Mtop,
                                                      float* __restrict__ out) {
  int xcd  = blockIdx.x & 7;
  int rest = blockIdx.x >> 3;     // 0..31
  int chunk = rest & 7;
  int bh    = (rest >> 3) * 8 + xcd;
  int b = bh >> 3, h = bh & 7;
  __shared__ alignas(16) float sc[UC][Ln];           // 40 KB scores->probs
  __shared__ alignas(16) float qs[UC][Dn];
  __shared__ alignas(16) float ks[UC][Dn];
  __shared__ float vs[UC][Dn];
  __shared__ alignas(16) float redp[8][UC][64];      // 10 KB partial attn@V
  __shared__ int   rows_s[UC];
  __shared__ float inv_s[UC];
  const float* Qb = Q + (size_t)bh * Ln * Dn;
  const float* Kb = K + (size_t)bh * Ln * Dn;
  const float* Vb = V + (size_t)bh * Ln * Dn;
  int tid = threadIdx.x;

  if (tid < UC * 64) {
    int u = tid >> 6, d = tid & 63;
    int row = Mtop[bh * NTOP + chunk * UC + u];
    if (d == 0) rows_s[u] = row;
    qs[u][d] = Qb[(size_t)row * Dn + d];
    ks[u][d] = Kb[(size_t)row * Dn + d];
    vs[u][d] = Vb[(size_t)row * Dn + d];
  }
  __syncthreads();

  // pass 1: scores[u][l] = 0.0625*(Qsel[u].K[l] + Q[l].Ksel[u]), causal mask l>row
  float acc[UC][4];
#pragma unroll
  for (int u = 0; u < UC; u++)
#pragma unroll
    for (int j = 0; j < 4; j++) acc[u][j] = 0.f;

  for (int tt = 0; tt < 4; tt++) {
    float4 kk[4][4], qq[4][4];    // [j][ts] — 32 loads issued before use
#pragma unroll
    for (int j = 0; j < 4; j++) {
      int l = tid + j * 512;
      const float4* kp = (const float4*)(Kb + (size_t)l * Dn) + tt * 4;
      const float4* qp = (const float4*)(Qb + (size_t)l * Dn) + tt * 4;
#pragma unroll
      for (int ts = 0; ts < 4; ts++) { kk[j][ts] = kp[ts]; qq[j][ts] = qp[ts]; }
    }
#pragma unroll
    for (int ts = 0; ts < 4; ts++) {
      int t = tt * 4 + ts;
#pragma unroll
      for (int u = 0; u < UC; u++) {
        float4 q4 = *(const float4*)(&qs[u][t * 4]);
        float4 k4 = *(const float4*)(&ks[u][t * 4]);
#pragma unroll
        for (int j = 0; j < 4; j++) {
          acc[u][j] += q4.x * kk[j][ts].x + q4.y * kk[j][ts].y
                     + q4.z * kk[j][ts].z + q4.w * kk[j][ts].w
                     + k4.x * qq[j][ts].x + k4.y * qq[j][ts].y
                     + k4.z * qq[j][ts].z + k4.w * qq[j][ts].w;
        }
      }
    }
  }
#pragma unroll
  for (int u = 0; u < UC; u++) {
    int row = rows_s[u];
#pragma unroll
    for (int j = 0; j < 4; j++) {
      int l = tid + j * 512;
      sc[u][l] = (l > row) ? -1e9f : acc[u][j] * 0.0625f;
    }
  }
  __syncthreads();

  // pass 2: softmax per u; wave w handles u=w (waves 0..4)
  int w = tid >> 6, lane = tid & 63;
  if (w < UC) {
    float mx = -INFINITY;
    for (int kq = 0; kq < 32; kq++) mx = fmaxf(mx, sc[w][lane + 64 * kq]);
    for (int off = 32; off; off >>= 1) mx = fmaxf(mx, __shfl_xor(mx, off, 64));
    float sum = 0.f;
    for (int kq = 0; kq < 32; kq++) {
      float e = __expf(sc[w][lane + 64 * kq] - mx);
      sc[w][lane + 64 * kq] = e;
      sum += e;
    }
    for (int off = 32; off; off >>= 1) sum += __shfl_xor(sum, off, 64);
    if (lane == 0) inv_s[w] = 1.0f / sum;
  }
  __syncthreads();

  // pass 3: attn @ V ; wave w owns l in [w*256, w*256+256) for ALL 5 u.
  {
    int quad = lane & 15, lr = lane >> 4;
    int l0w = w * 256;
    const float4* V4 = (const float4*)Vb;
    float4 a[UC];
#pragma unroll
    for (int u = 0; u < UC; u++) a[u] = make_float4(0.f, 0.f, 0.f, 0.f);
    for (int it4 = 0; it4 < 16; it4++) {
      int lb = l0w + lr + it4 * 16;
      float4 v0 = V4[(size_t)(lb)      * 16 + quad];
      float4 v1 = V4[(size_t)(lb + 4)  * 16 + quad];
      float4 v2 = V4[(size_t)(lb + 8)  * 16 + quad];
      float4 v3 = V4[(size_t)(lb + 12) * 16 + quad];
#pragma unroll
      for (int u = 0; u < UC; u++) {
        float s0 = sc[u][lb], s1 = sc[u][lb + 4], s2 = sc[u][lb + 8], s3 = sc[u][lb + 12];
        a[u].x += s0 * v0.x + s1 * v1.x + s2 * v2.x + s3 * v3.x;
        a[u].y += s0 * v0.y + s1 * v1.y + s2 * v2.y + s3 * v3.y;
        a[u].z += s0 * v0.z + s1 * v1.z + s2 * v2.z + s3 * v3.z;
        a[u].w += s0 * v0.w + s1 * v1.w + s2 * v2.w + s3 * v3.w;
      }
    }
#pragma unroll
    for (int u = 0; u < UC; u++) {
#pragma unroll
      for (int off = 16; off < 64; off <<= 1) {
        a[u].x += __shfl_xor(a[u].x, off, 64);
        a[u].y += __shfl_xor(a[u].y, off, 64);
        a[u].z += __shfl_xor(a[u].z, off, 64);
        a[u].w += __shfl_xor(a[u].w, off, 64);
      }
      if (lr == 0) *(float4*)(&redp[w][u][quad * 4]) = a[u];
    }
  }
  __syncthreads();

  if (w < UC) {
    float r = 0.f;
#pragma unroll
    for (int g = 0; g < 8; g++) r += redp[g][w][lane];
    float outv = 0.5f * (vs[w][lane] + r * inv_s[w]);
    int row = rows_s[w];
    out[(((size_t)b * Ln + row) * Hn + h) * Dn + lane] = outv;
  }
}

extern "C" void kernel_launch(void* const* d_in, const int* in_sizes, int n_in,
                              void* d_out, int out_size, void* d_ws, size_t ws_size,
                              hipStream_t stream) {
  const float* Q = (const float*)d_in[0];  // (B,L,H,D) flat == (B,H,L,D) reshape
  const float* K = (const float*)d_in[1];
  const float* V = (const float*)d_in[2];
  float* out = (float*)d_out;
  char* ws = (char*)d_ws;

  float* M       = (float*)(ws + NSAMP * 4);                       // 256 KB
  int*   Mtop    = (int*)(ws + NSAMP * 4 + BHn * Ln * 4);          // 5 KB
  float* partial = (float*)(ws + NSAMP * 4 + BHn * Ln * 4 + BHn * NTOP * 4); // 256 KB

  // Partitionable threefry split of key(42) = (0,42): k2 = tf(key, ctr=(0,1)).
  uint32_t s0 = 0u, s1 = 1u;
  tf2x32(0u, 42u, s0, s1);

  // 3 launches: {vsum || compute_M} -> {topk || context_write} -> sparse_attn
  fused_m_vsum<<<1024 + 4096, 256, 0, stream>>>(Q, K, V, M, partial, s0, s1);
  fused_topk_ctx<<<32 + 1024, 256, 0, stream>>>(M, Mtop, V, partial, out);
  sparse_attn<<<BHn * 8, 512, 0, stream>>>(Q, K, V, Mtop, out);
}

// Round 6
// 180.726 us; speedup vs baseline: 2.2949x; 1.1979x over previous
//
#include <hip/hip_runtime.h>
#include <stdint.h>
#include <math.h>

// Problem constants (B,L,H,D fixed by setup_inputs)
#define Bn 4
#define Ln 2048
#define Hn 8
#define Dn 64
#define BHn (Bn*Hn)
#define NTOP 40   // FACTOR * ceil(log(2048)) = 5*8
#define SK   40
#define NSAMP (Ln*SK)        // 81920

// ---------------- Threefry-2x32 (exact JAX replication) ----------------
__host__ __device__ inline uint32_t rotl32(uint32_t x, int r) {
  return (x << r) | (x >> (32 - r));
}

__host__ __device__ inline void tf2x32(uint32_t k0, uint32_t k1,
                                       uint32_t& x0, uint32_t& x1) {
  const uint32_t ks2 = k0 ^ k1 ^ 0x1BD11BDAu;
  const int RA[4] = {13, 15, 26, 6};
  const int RB[4] = {17, 29, 16, 24};
  x0 += k0; x1 += k1;
  for (int i = 0; i < 4; i++) { x0 += x1; x1 = rotl32(x1, RA[i]); x1 ^= x0; }
  x0 += k1;  x1 += ks2 + 1u;
  for (int i = 0; i < 4; i++) { x0 += x1; x1 = rotl32(x1, RB[i]); x1 ^= x0; }
  x0 += ks2; x1 += k0 + 2u;
  for (int i = 0; i < 4; i++) { x0 += x1; x1 = rotl32(x1, RA[i]); x1 ^= x0; }
  x0 += k0;  x1 += k1 + 3u;
  for (int i = 0; i < 4; i++) { x0 += x1; x1 = rotl32(x1, RB[i]); x1 ^= x0; }
  x0 += k1;  x1 += ks2 + 4u;
  for (int i = 0; i < 4; i++) { x0 += x1; x1 = rotl32(x1, RA[i]); x1 ^= x0; }
  x0 += ks2; x1 += k0 + 5u;
}

// jax_threefry_partitionable=True: elem n -> ctr (0, n); draw = out0 ^ out1
__device__ inline int draw2048(uint32_t k0, uint32_t k1, uint32_t n) {
  uint32_t a = 0u, b = n;
  tf2x32(k0, k1, a, b);
  return (int)((a ^ b) & (Ln - 1));
}

// ---------------- DPP 16-lane sum reduce (VALU pipe, zero DS ops) ----------------
template<int CTRL>
__device__ __forceinline__ float dpp_add(float x) {
  int y = __builtin_amdgcn_update_dpp(0, __float_as_int(x), CTRL, 0xF, 0xF, true);
  return x + __int_as_float(y);
}
__device__ __forceinline__ float red16(float d) {
  d = dpp_add<0xB1>(d);   // quad_perm [1,0,3,2]  (xor 1)
  d = dpp_add<0x4E>(d);   // quad_perm [2,3,0,1]  (xor 2)
  d = dpp_add<0x141>(d);  // row_half_mirror      (pairs across 8-halves)
  d = dpp_add<0x140>(d);  // row_mirror           (pairs across 16-row)
  return d;
}

// ---------------- fused launch 1: vsum_partial (blocks 0..1023) +
//                  compute_M (blocks 1024..5119) ---------------- (proven R5)
__global__ __launch_bounds__(256) void fused_m_vsum(const float* __restrict__ Q,
                                                    const float* __restrict__ K,
                                                    const float* __restrict__ V,
                                                    float* __restrict__ M,
                                                    float* __restrict__ partial,
                                                    uint32_t k0, uint32_t k1) {
  __shared__ alignas(16) int sidx[16][40];   // compute_M path (2.5 KB)
  __shared__ float red[4][64];               // vsum path (1 KB)

  if (blockIdx.x < 1024) {
    // ---- vsum_partial: per-tile (64 l) V sums ----
    int bid  = blockIdx.x;
    int tile = bid & 31;
    int bh   = bid >> 5;
    int d = threadIdx.x & 63;
    int g = threadIdx.x >> 6;
    const float* Vb = V + (size_t)bh * Ln * Dn;
    int l0 = tile * 64 + g * 16;
    float s = 0.f;
    for (int j = 0; j < 16; j++) s += Vb[(size_t)(l0 + j) * Dn + d];
    red[g][d] = s;
    __syncthreads();
    if (g == 0)
      partial[((size_t)bh * 32 + tile) * 64 + d] =
          red[0][d] + red[1][d] + red[2][d] + red[3][d];
    return;
  }

  // ---- compute_M v3: quarter-wave-cooperative gather, LDS index table, DPP ----
  int cmb = blockIdx.x - 1024;        // 0..4095; 1024%8==0 keeps xcd mapping
  int xcd = cmb & 7;
  int idx = cmb >> 3;                 // 0..511
  int bh  = (idx & 3) * 8 + xcd;      // {xcd, xcd+8, xcd+16, xcd+24}
  int seg = idx >> 2;                 // 0..127
  int tid = threadIdx.x;
  int qw  = tid >> 4;                 // query slot in wg: 0..15
  int j   = tid & 15;                 // lane within quarter-wave
  int i   = seg * 16 + qw;            // query index

  uint32_t n0 = (uint32_t)(i * SK);
  sidx[qw][j]      = draw2048(k0, k1, n0 + j);
  sidx[qw][16 + j] = draw2048(k0, k1, n0 + 16 + j);
  if (j < 8) sidx[qw][32 + j] = draw2048(k0, k1, n0 + 32 + j);

  const float* Qb = Q + ((size_t)bh * Ln + i) * Dn;
  float4 qf = ((const float4*)Qb)[j];
  __syncthreads();

  int4 I[10];
#pragma unroll
  for (int t = 0; t < 10; t++) I[t] = *(const int4*)&sidx[qw][t * 4];

  const float* Kb = K + (size_t)bh * Ln * Dn;
  float mx = -INFINITY, sm = 0.f;
#pragma unroll
  for (int t = 0; t < 10; t++) {
    int ls[4] = {I[t].x, I[t].y, I[t].z, I[t].w};
#pragma unroll
    for (int c = 0; c < 4; c++) {
      float4 kf = ((const float4*)(Kb + (size_t)ls[c] * Dn))[j];
      float d = qf.x * kf.x + qf.y * kf.y + qf.z * kf.z + qf.w * kf.w;
      d = red16(d);                    // full 64-elem dot in every lane
      mx = fmaxf(mx, d);
      sm += d;
    }
  }
  if (j == 0)
    M[(size_t)bh * Ln + i] = mx - sm * (1.0f / (float)Ln);
}

// ---------------- launch 2: unordered exact top-40 via bisection select ----------------
// R5 counters: old topk was the 56 us tail of fused_topk_ctx at 3.5% VALUBusy --
// 80 serial argmax rounds x 6-deep shfl chains on 32 of 256 CUs. Replacement:
// ORDER-FREE selection (valid because M_top's order is semantically dead in the
// reference: distinct indices, per-row updates, scatter). Binary search on
// monotonic uint32 keys for the 40th-largest value K40; counts via
// __ballot/popcll (VALU/SALU, no cross-lane latency chains, 1 barrier/step).
// Then compact {key > K40} + smallest-index ties. ~4 us vs ~50 us.
__global__ __launch_bounds__(256) void topk_select(const float* __restrict__ M,
                                                   int* __restrict__ Mtop) {
  int bh = blockIdx.x;
  int tid = threadIdx.x;
  const float* m = M + (size_t)bh * Ln;

  // 8 contiguous values per thread (2x dwordx4), monotonic keys
  uint32_t k[8]; int li[8];
  float4 va = ((const float4*)m)[tid * 2];
  float4 vb = ((const float4*)m)[tid * 2 + 1];
  float vals[8] = {va.x, va.y, va.z, va.w, vb.x, vb.y, vb.z, vb.w};
#pragma unroll
  for (int j = 0; j < 8; j++) {
    uint32_t u = __float_as_uint(vals[j]);
    k[j] = (u & 0x80000000u) ? ~u : (u | 0x80000000u);
    li[j] = tid * 8 + j;
  }

  __shared__ int cnts[32];
  __shared__ int cA, outc, eqn2;
  __shared__ int eqbuf[2048];
  if (tid < 32) cnts[tid] = 0;
  if (tid == 0) { cA = 0; outc = 0; eqn2 = 0; }
  __syncthreads();

  // find K40 = max T with count(key >= T) >= NTOP
  uint32_t lo = 0u, hi = 0xFFFFFFFFu;
  for (int it = 0; it < 32; ++it) {
    if (lo >= hi) break;                       // uniform across block
    uint32_t mid = lo + ((hi - lo) >> 1) + 1u; // in (lo, hi], no overflow
    int cw = 0;
#pragma unroll
    for (int j = 0; j < 8; j++)
      cw += __popcll(__ballot(k[j] >= mid));
    if ((tid & 63) == 0) atomicAdd(&cnts[it], cw);
    __syncthreads();
    int total = cnts[it];
    if (total >= NTOP) lo = mid; else hi = mid - 1u;
  }
  uint32_t K40 = lo;

  // count strictly-above
  {
    int cw = 0;
#pragma unroll
    for (int j = 0; j < 8; j++)
      cw += __popcll(__ballot(k[j] > K40));
    if ((tid & 63) == 0) atomicAdd(&cA, cw);
  }
  __syncthreads();

  // compact: strictly-greater (any order), ties into eqbuf
#pragma unroll
  for (int j = 0; j < 8; j++) {
    if (k[j] > K40) {
      int p = atomicAdd(&outc, 1);
      Mtop[bh * NTOP + p] = li[j];
    } else if (k[j] == K40) {
      int p = atomicAdd(&eqn2, 1);
      eqbuf[p] = li[j];
    }
  }
  __syncthreads();

  if (tid == 0) {
    int need = NTOP - cA;        // >= 1 by construction of K40
    int n = eqn2;
    for (int s = 0; s < need; s++) {   // typically need==1, n==1
      int best = 0x7fffffff, bi = 0;
      for (int t = 0; t < n; t++)
        if (eqbuf[t] < best) { best = eqbuf[t]; bi = t; }
      Mtop[bh * NTOP + cA + s] = best;
      eqbuf[bi] = 0x7fffffff;
    }
  }
}

// ---------------- launch 3: sparse attention (blocks 0..255, VERBATIM proven)
//                  + context_write (blocks 256..767, 512-thr rework) ----------------
// Context is pure BW and hides under sparse's ~56 us latency shadow. Write race
// on the 40 selected rows is removed by an LDS bitmask: context SKIPS them
// (sparse owns those rows; reference overwrites them anyway). Sparse path is
// byte-identical to the R0/R5-proven 512-thread/128-VGPR structure.
// Tripwire: launch-3 WRITE_SIZE should be ~17 MB; >>20 MB means spill returned.
#define UC 5
#define SPB 256
__global__ __launch_bounds__(512, 2) void sparse_ctx(const float* __restrict__ Q,
                                                     const float* __restrict__ K,
                                                     const float* __restrict__ V,
                                                     const int* __restrict__ Mtop,
                                                     const float* __restrict__ partial,
                                                     float* __restrict__ out) {
  __shared__ alignas(16) float sc[UC][Ln];           // 40 KB scores->probs
  __shared__ alignas(16) float qs[UC][Dn];
  __shared__ alignas(16) float ks[UC][Dn];
  __shared__ float vs[UC][Dn];
  __shared__ alignas(16) float redp[8][UC][64];      // 10 KB partial attn@V
  __shared__ int   rows_s[UC];
  __shared__ float inv_s[UC];
  __shared__ alignas(16) float credR[8][64];         // ctx path (2 KB)
  __shared__ uint32_t cmask[64];                     // ctx path: selected-row bits

  if (blockIdx.x >= SPB) {
    // ---- context_write: prefix + cumsum + transposed write, skip selected ----
    int bid = blockIdx.x - SPB;      // 0..511
    int bh  = bid >> 4;              // 0..31
    int T   = bid & 15;              // 128-l tile
    int b = bh >> 3, h = bh & 7;
    int tid = threadIdx.x, d = tid & 63, g = tid >> 6;   // g 0..7
    if (tid < 64) cmask[tid] = 0u;
    __syncthreads();
    if (tid < NTOP) {
      int r = Mtop[bh * NTOP + tid];
      atomicOr(&cmask[r >> 5], 1u << (r & 31));
    }
    float p = 0.f;
    for (int t = g; t < 2 * T; t += 8)
      p += partial[((size_t)bh * 32 + t) * 64 + d];
    credR[g][d] = p;
    __syncthreads();                 // also fences cmask population
    float prefix = 0.f;
#pragma unroll
    for (int gg = 0; gg < 8; gg++) prefix += credR[gg][d];
    __syncthreads();
    const float* Vb = V + (size_t)bh * Ln * Dn;
    int l0 = T * 128 + g * 16;
    float vloc[16]; float s = 0.f;
    for (int j = 0; j < 16; j++) {
      vloc[j] = Vb[(size_t)(l0 + j) * Dn + d];
      s += vloc[j];
    }
    credR[g][d] = s;
    __syncthreads();
    float running = prefix;
    for (int gg = 0; gg < g; gg++) running += credR[gg][d];
    for (int j = 0; j < 16; j++) {
      int l = l0 + j;
      running += vloc[j];
      if (!((cmask[l >> 5] >> (l & 31)) & 1u))
        out[(((size_t)b * Ln + l) * Hn + h) * Dn + d] =
            0.5f * ((float)(l + 1) * vloc[j] + running);
    }
    return;
  }

  // ---- sparse attention over 5 selected rows (VERBATIM R5) ----
  int xcd  = blockIdx.x & 7;
  int rest = blockIdx.x >> 3;     // 0..31
  int chunk = rest & 7;
  int bh    = (rest >> 3) * 8 + xcd;
  int b = bh >> 3, h = bh & 7;
  const float* Qb = Q + (size_t)bh * Ln * Dn;
  const float* Kb = K + (size_t)bh * Ln * Dn;
  const float* Vb = V + (size_t)bh * Ln * Dn;
  int tid = threadIdx.x;

  if (tid < UC * 64) {
    int u = tid >> 6, d = tid & 63;
    int row = Mtop[bh * NTOP + chunk * UC + u];
    if (d == 0) rows_s[u] = row;
    qs[u][d] = Qb[(size_t)row * Dn + d];
    ks[u][d] = Kb[(size_t)row * Dn + d];
    vs[u][d] = Vb[(size_t)row * Dn + d];
  }
  __syncthreads();

  // pass 1: scores[u][l] = 0.0625*(Qsel[u].K[l] + Q[l].Ksel[u]), causal mask l>row
  float acc[UC][4];
#pragma unroll
  for (int u = 0; u < UC; u++)
#pragma unroll
    for (int j = 0; j < 4; j++) acc[u][j] = 0.f;

  for (int tt = 0; tt < 4; tt++) {
    float4 kk[4][4], qq[4][4];    // [j][ts] — 32 loads issued before use
#pragma unroll
    for (int j = 0; j < 4; j++) {
      int l = tid + j * 512;
      const float4* kp = (const float4*)(Kb + (size_t)l * Dn) + tt * 4;
      const float4* qp = (const float4*)(Qb + (size_t)l * Dn) + tt * 4;
#pragma unroll
      for (int ts = 0; ts < 4; ts++) { kk[j][ts] = kp[ts]; qq[j][ts] = qp[ts]; }
    }
#pragma unroll
    for (int ts = 0; ts < 4; ts++) {
      int t = tt * 4 + ts;
#pragma unroll
      for (int u = 0; u < UC; u++) {
        float4 q4 = *(const float4*)(&qs[u][t * 4]);
        float4 k4 = *(const float4*)(&ks[u][t * 4]);
#pragma unroll
        for (int j = 0; j < 4; j++) {
          acc[u][j] += q4.x * kk[j][ts].x + q4.y * kk[j][ts].y
                     + q4.z * kk[j][ts].z + q4.w * kk[j][ts].w
                     + k4.x * qq[j][ts].x + k4.y * qq[j][ts].y
                     + k4.z * qq[j][ts].z + k4.w * qq[j][ts].w;
        }
      }
    }
  }
#pragma unroll
  for (int u = 0; u < UC; u++) {
    int row = rows_s[u];
#pragma unroll
    for (int j = 0; j < 4; j++) {
      int l = tid + j * 512;
      sc[u][l] = (l > row) ? -1e9f : acc[u][j] * 0.0625f;
    }
  }
  __syncthreads();

  // pass 2: softmax per u; wave w handles u=w (waves 0..4)
  int w = tid >> 6, lane = tid & 63;
  if (w < UC) {
    float mx = -INFINITY;
    for (int kq = 0; kq < 32; kq++) mx = fmaxf(mx, sc[w][lane + 64 * kq]);
    for (int off = 32; off; off >>= 1) mx = fmaxf(mx, __shfl_xor(mx, off, 64));
    float sum = 0.f;
    for (int kq = 0; kq < 32; kq++) {
      float e = __expf(sc[w][lane + 64 * kq] - mx);
      sc[w][lane + 64 * kq] = e;
      sum += e;
    }
    for (int off = 32; off; off >>= 1) sum += __shfl_xor(sum, off, 64);
    if (lane == 0) inv_s[w] = 1.0f / sum;
  }
  __syncthreads();

  // pass 3: attn @ V ; wave w owns l in [w*256, w*256+256) for ALL 5 u.
  {
    int quad = lane & 15, lr = lane >> 4;
    int l0w = w * 256;
    const float4* V4 = (const float4*)Vb;
    float4 a[UC];
#pragma unroll
    for (int u = 0; u < UC; u++) a[u] = make_float4(0.f, 0.f, 0.f, 0.f);
    for (int it4 = 0; it4 < 16; it4++) {
      int lb = l0w + lr + it4 * 16;
      float4 v0 = V4[(size_t)(lb)      * 16 + quad];
      float4 v1 = V4[(size_t)(lb + 4)  * 16 + quad];
      float4 v2 = V4[(size_t)(lb + 8)  * 16 + quad];
      float4 v3 = V4[(size_t)(lb + 12) * 16 + quad];
#pragma unroll
      for (int u = 0; u < UC; u++) {
        float s0 = sc[u][lb], s1 = sc[u][lb + 4], s2 = sc[u][lb + 8], s3 = sc[u][lb + 12];
        a[u].x += s0 * v0.x + s1 * v1.x + s2 * v2.x + s3 * v3.x;
        a[u].y += s0 * v0.y + s1 * v1.y + s2 * v2.y + s3 * v3.y;
        a[u].z += s0 * v0.z + s1 * v1.z + s2 * v2.z + s3 * v3.z;
        a[u].w += s0 * v0.w + s1 * v1.w + s2 * v2.w + s3 * v3.w;
      }
    }
#pragma unroll
    for (int u = 0; u < UC; u++) {
#pragma unroll
      for (int off = 16; off < 64; off <<= 1) {
        a[u].x += __shfl_xor(a[u].x, off, 64);
        a[u].y += __shfl_xor(a[u].y, off, 64);
        a[u].z += __shfl_xor(a[u].z, off, 64);
        a[u].w += __shfl_xor(a[u].w, off, 64);
      }
      if (lr == 0) *(float4*)(&redp[w][u][quad * 4]) = a[u];
    }
  }
  __syncthreads();

  if (w < UC) {
    float r = 0.f;
#pragma unroll
    for (int g = 0; g < 8; g++) r += redp[g][w][lane];
    float outv = 0.5f * (vs[w][lane] + r * inv_s[w]);
    int row = rows_s[w];
    out[(((size_t)b * Ln + row) * Hn + h) * Dn + lane] = outv;
  }
}

extern "C" void kernel_launch(void* const* d_in, const int* in_sizes, int n_in,
                              void* d_out, int out_size, void* d_ws, size_t ws_size,
                              hipStream_t stream) {
  const float* Q = (const float*)d_in[0];  // (B,L,H,D) flat == (B,H,L,D) reshape
  const float* K = (const float*)d_in[1];
  const float* V = (const float*)d_in[2];
  float* out = (float*)d_out;
  char* ws = (char*)d_ws;

  float* M       = (float*)(ws + NSAMP * 4);                       // 256 KB
  int*   Mtop    = (int*)(ws + NSAMP * 4 + BHn * Ln * 4);          // 5 KB
  float* partial = (float*)(ws + NSAMP * 4 + BHn * Ln * 4 + BHn * NTOP * 4); // 256 KB

  // Partitionable threefry split of key(42) = (0,42): k2 = tf(key, ctr=(0,1)).
  uint32_t s0 = 0u, s1 = 1u;
  tf2x32(0u, 42u, s0, s1);

  // 3 launches: {vsum || compute_M} -> topk_select -> {sparse_attn || context}
  fused_m_vsum<<<1024 + 4096, 256, 0, stream>>>(Q, K, V, M, partial, s0, s1);
  topk_select<<<BHn, 256, 0, stream>>>(M, Mtop);
  sparse_ctx<<<SPB + 512, 512, 0, stream>>>(Q, K, V, Mtop, partial, out);
}

// Round 7
// 178.316 us; speedup vs baseline: 2.3259x; 1.0135x over previous
//
#include <hip/hip_runtime.h>
#include <stdint.h>
#include <math.h>

// Problem constants (B,L,H,D fixed by setup_inputs)
#define Bn 4
#define Ln 2048
#define Hn 8
#define Dn 64
#define BHn (Bn*Hn)
#define NTOP 40   // FACTOR * ceil(log(2048)) = 5*8
#define SK   40
#define NSAMP (Ln*SK)        // 81920

// ---------------- Threefry-2x32 (exact JAX replication) ----------------
__host__ __device__ inline uint32_t rotl32(uint32_t x, int r) {
  return (x << r) | (x >> (32 - r));
}

__host__ __device__ inline void tf2x32(uint32_t k0, uint32_t k1,
                                       uint32_t& x0, uint32_t& x1) {
  const uint32_t ks2 = k0 ^ k1 ^ 0x1BD11BDAu;
  const int RA[4] = {13, 15, 26, 6};
  const int RB[4] = {17, 29, 16, 24};
  x0 += k0; x1 += k1;
  for (int i = 0; i < 4; i++) { x0 += x1; x1 = rotl32(x1, RA[i]); x1 ^= x0; }
  x0 += k1;  x1 += ks2 + 1u;
  for (int i = 0; i < 4; i++) { x0 += x1; x1 = rotl32(x1, RB[i]); x1 ^= x0; }
  x0 += ks2; x1 += k0 + 2u;
  for (int i = 0; i < 4; i++) { x0 += x1; x1 = rotl32(x1, RA[i]); x1 ^= x0; }
  x0 += k0;  x1 += k1 + 3u;
  for (int i = 0; i < 4; i++) { x0 += x1; x1 = rotl32(x1, RB[i]); x1 ^= x0; }
  x0 += k1;  x1 += ks2 + 4u;
  for (int i = 0; i < 4; i++) { x0 += x1; x1 = rotl32(x1, RA[i]); x1 ^= x0; }
  x0 += ks2; x1 += k0 + 5u;
}

// jax_threefry_partitionable=True: elem n -> ctr (0, n); draw = out0 ^ out1
__device__ inline int draw2048(uint32_t k0, uint32_t k1, uint32_t n) {
  uint32_t a = 0u, b = n;
  tf2x32(k0, k1, a, b);
  return (int)((a ^ b) & (Ln - 1));
}

// ---------------- DPP 16-lane sum reduce (VALU pipe, zero DS ops) ----------------
template<int CTRL>
__device__ __forceinline__ float dpp_add(float x) {
  int y = __builtin_amdgcn_update_dpp(0, __float_as_int(x), CTRL, 0xF, 0xF, true);
  return x + __int_as_float(y);
}
__device__ __forceinline__ float red16(float d) {
  d = dpp_add<0xB1>(d);   // quad_perm [1,0,3,2]  (xor 1)
  d = dpp_add<0x4E>(d);   // quad_perm [2,3,0,1]  (xor 2)
  d = dpp_add<0x141>(d);  // row_half_mirror      (pairs across 8-halves)
  d = dpp_add<0x140>(d);  // row_mirror           (pairs across 16-row)
  return d;
}

// ---------------- fused launch 1: vsum_partial (blocks 0..1023) +
//                  compute_M v4 (blocks 1024..9215) ----------------
// compute_M v4 (R6's counters: latency-bound, VALU ~32%, occ 44%, ~4 loads in
// flight per quarter-wave, 40-sample serial chain). Three structure-preserving
// latency levers: (a) each query owned by a 32-lane HALF-wave; its two
// quarter-waves split the 40 samples 20/20 (serial chain halved), merged by
// one shfl_xor(16) pair at the end; (b) 8 queries/block -> 8192 compute
// blocks (2x TLP); (c) depth-1 group prefetch (8 gather loads in flight).
// Threefry draws and per-sample dot/red16 are bit-identical; only the sm
// accumulation splits 20+20 (1 reassociation, absorbed by tolerance).
__global__ __launch_bounds__(256) void fused_m_vsum(const float* __restrict__ Q,
                                                    const float* __restrict__ K,
                                                    const float* __restrict__ V,
                                                    float* __restrict__ M,
                                                    float* __restrict__ partial,
                                                    uint32_t k0, uint32_t k1) {
  __shared__ alignas(16) int sidx[8][40];    // compute_M path (1.25 KB)
  __shared__ float red[4][64];               // vsum path (1 KB)

  if (blockIdx.x < 1024) {
    // ---- vsum_partial: per-tile (64 l) V sums ----
    int bid  = blockIdx.x;
    int tile = bid & 31;
    int bh   = bid >> 5;
    int d = threadIdx.x & 63;
    int g = threadIdx.x >> 6;
    const float* Vb = V + (size_t)bh * Ln * Dn;
    int l0 = tile * 64 + g * 16;
    float s = 0.f;
    for (int j = 0; j < 16; j++) s += Vb[(size_t)(l0 + j) * Dn + d];
    red[g][d] = s;
    __syncthreads();
    if (g == 0)
      partial[((size_t)bh * 32 + tile) * 64 + d] =
          red[0][d] + red[1][d] + red[2][d] + red[3][d];
    return;
  }

  int cmb = blockIdx.x - 1024;        // 0..8191; 1024%8==0 keeps xcd mapping
  int xcd = cmb & 7;
  int idx = cmb >> 3;                 // 0..1023
  int bh  = (idx & 3) * 8 + xcd;      // {xcd, xcd+8, xcd+16, xcd+24}
  int seg = idx >> 2;                 // 0..255
  int tid = threadIdx.x;
  int q   = tid >> 5;                 // query slot in wg: 0..7
  int h   = tid & 31;                 // lane within half-wave
  int j   = h & 15;                   // float4 slot within row
  int p   = h >> 4;                   // sample-half: samples [p*20, p*20+20)
  int i   = seg * 8 + q;              // query index

  // index gen: thread (q, l=h) draws sample l; l<8 also draws 32+l
  {
    uint32_t n0 = (uint32_t)(i * SK);
    sidx[q][h] = draw2048(k0, k1, n0 + h);
    if (h < 8) sidx[q][32 + h] = draw2048(k0, k1, n0 + 32 + h);
  }

  const float* Qb = Q + ((size_t)bh * Ln + i) * Dn;
  float4 qf = ((const float4*)Qb)[j];
  __syncthreads();

  // this half's 20 indices (5 int4 groups; p*20*4B = 80B, 16B-aligned)
  int4 I[5];
#pragma unroll
  for (int t = 0; t < 5; t++) I[t] = *(const int4*)&sidx[q][p * 20 + t * 4];

  const float* Kb = K + (size_t)bh * Ln * Dn;
  float mx = -INFINITY, sm = 0.f;

  float4 kf[4], kn[4];
  {
    int ls[4] = {I[0].x, I[0].y, I[0].z, I[0].w};
#pragma unroll
    for (int c = 0; c < 4; c++)
      kf[c] = ((const float4*)(Kb + (size_t)ls[c] * Dn))[j];
  }
#pragma unroll
  for (int t = 0; t < 5; t++) {
    if (t < 4) {                       // depth-1 group prefetch (8 in flight)
      int ls[4] = {I[t + 1].x, I[t + 1].y, I[t + 1].z, I[t + 1].w};
#pragma unroll
      for (int c = 0; c < 4; c++)
        kn[c] = ((const float4*)(Kb + (size_t)ls[c] * Dn))[j];
    }
#pragma unroll
    for (int c = 0; c < 4; c++) {
      float d = qf.x * kf[c].x + qf.y * kf[c].y + qf.z * kf[c].z + qf.w * kf[c].w;
      d = red16(d);                    // full 64-elem dot in every lane
      mx = fmaxf(mx, d);
      sm += d;
    }
    if (t < 4) {
#pragma unroll
      for (int c = 0; c < 4; c++) kf[c] = kn[c];
    }
  }
  // merge the two 20-sample halves (stays within the 32-lane half-wave)
  mx = fmaxf(mx, __shfl_xor(mx, 16, 64));
  sm += __shfl_xor(sm, 16, 64);
  if (h == 0)
    M[(size_t)bh * Ln + i] = mx - sm * (1.0f / (float)Ln);
}

// ---------------- launch 2: unordered exact top-40 via bisection select ----------------
// (proven R6: order-free selection is valid because M_top's order is
// semantically dead in the reference — distinct indices, per-row updates,
// scatter. Binary search for the 40th-largest monotonic key via
// __ballot/popcll counts; compact {key > K40}; smallest-index ties.)
__global__ __launch_bounds__(256) void topk_select(const float* __restrict__ M,
                                                   int* __restrict__ Mtop) {
  int bh = blockIdx.x;
  int tid = threadIdx.x;
  const float* m = M + (size_t)bh * Ln;

  // 8 contiguous values per thread (2x dwordx4), monotonic keys
  uint32_t k[8]; int li[8];
  float4 va = ((const float4*)m)[tid * 2];
  float4 vb = ((const float4*)m)[tid * 2 + 1];
  float vals[8] = {va.x, va.y, va.z, va.w, vb.x, vb.y, vb.z, vb.w};
#pragma unroll
  for (int j = 0; j < 8; j++) {
    uint32_t u = __float_as_uint(vals[j]);
    k[j] = (u & 0x80000000u) ? ~u : (u | 0x80000000u);
    li[j] = tid * 8 + j;
  }

  __shared__ int cnts[32];
  __shared__ int cA, outc, eqn2;
  __shared__ int eqbuf[2048];
  if (tid < 32) cnts[tid] = 0;
  if (tid == 0) { cA = 0; outc = 0; eqn2 = 0; }
  __syncthreads();

  // find K40 = max T with count(key >= T) >= NTOP
  uint32_t lo = 0u, hi = 0xFFFFFFFFu;
  for (int it = 0; it < 32; ++it) {
    if (lo >= hi) break;                       // uniform across block
    uint32_t mid = lo + ((hi - lo) >> 1) + 1u; // in (lo, hi], no overflow
    int cw = 0;
#pragma unroll
    for (int j = 0; j < 8; j++)
      cw += __popcll(__ballot(k[j] >= mid));
    if ((tid & 63) == 0) atomicAdd(&cnts[it], cw);
    __syncthreads();
    int total = cnts[it];
    if (total >= NTOP) lo = mid; else hi = mid - 1u;
  }
  uint32_t K40 = lo;

  // count strictly-above
  {
    int cw = 0;
#pragma unroll
    for (int j = 0; j < 8; j++)
      cw += __popcll(__ballot(k[j] > K40));
    if ((tid & 63) == 0) atomicAdd(&cA, cw);
  }
  __syncthreads();

  // compact: strictly-greater (any order), ties into eqbuf
#pragma unroll
  for (int j = 0; j < 8; j++) {
    if (k[j] > K40) {
      int p = atomicAdd(&outc, 1);
      Mtop[bh * NTOP + p] = li[j];
    } else if (k[j] == K40) {
      int p = atomicAdd(&eqn2, 1);
      eqbuf[p] = li[j];
    }
  }
  __syncthreads();

  if (tid == 0) {
    int need = NTOP - cA;        // >= 1 by construction of K40
    int n = eqn2;
    for (int s = 0; s < need; s++) {   // typically need==1, n==1
      int best = 0x7fffffff, bi = 0;
      for (int t = 0; t < n; t++)
        if (eqbuf[t] < best) { best = eqbuf[t]; bi = t; }
      Mtop[bh * NTOP + cA + s] = best;
      eqbuf[bi] = 0x7fffffff;
    }
  }
}

// ---------------- launch 3: sparse attention (blocks 0..255, VERBATIM proven)
//                  + context_write (blocks 256..767) ---------------- (proven R6)
// Tripwire: launch-3 WRITE_SIZE ~21 MB; >>25 MB means spill returned.
#define UC 5
#define SPB 256
__global__ __launch_bounds__(512, 2) void sparse_ctx(const float* __restrict__ Q,
                                                     const float* __restrict__ K,
                                                     const float* __restrict__ V,
                                                     const int* __restrict__ Mtop,
                                                     const float* __restrict__ partial,
                                                     float* __restrict__ out) {
  __shared__ alignas(16) float sc[UC][Ln];           // 40 KB scores->probs
  __shared__ alignas(16) float qs[UC][Dn];
  __shared__ alignas(16) float ks[UC][Dn];
  __shared__ float vs[UC][Dn];
  __shared__ alignas(16) float redp[8][UC][64];      // 10 KB partial attn@V
  __shared__ int   rows_s[UC];
  __shared__ float inv_s[UC];
  __shared__ alignas(16) float credR[8][64];         // ctx path (2 KB)
  __shared__ uint32_t cmask[64];                     // ctx path: selected-row bits

  if (blockIdx.x >= SPB) {
    // ---- context_write: prefix + cumsum + transposed write, skip selected ----
    int bid = blockIdx.x - SPB;      // 0..511
    int bh  = bid >> 4;              // 0..31
    int T   = bid & 15;              // 128-l tile
    int b = bh >> 3, h = bh & 7;
    int tid = threadIdx.x, d = tid & 63, g = tid >> 6;   // g 0..7
    if (tid < 64) cmask[tid] = 0u;
    __syncthreads();
    if (tid < NTOP) {
      int r = Mtop[bh * NTOP + tid];
      atomicOr(&cmask[r >> 5], 1u << (r & 31));
    }
    float p = 0.f;
    for (int t = g; t < 2 * T; t += 8)
      p += partial[((size_t)bh * 32 + t) * 64 + d];
    credR[g][d] = p;
    __syncthreads();                 // also fences cmask population
    float prefix = 0.f;
#pragma unroll
    for (int gg = 0; gg < 8; gg++) prefix += credR[gg][d];
    __syncthreads();
    const float* Vb = V + (size_t)bh * Ln * Dn;
    int l0 = T * 128 + g * 16;
    float vloc[16]; float s = 0.f;
    for (int j = 0; j < 16; j++) {
      vloc[j] = Vb[(size_t)(l0 + j) * Dn + d];
      s += vloc[j];
    }
    credR[g][d] = s;
    __syncthreads();
    float running = prefix;
    for (int gg = 0; gg < g; gg++) running += credR[gg][d];
    for (int j = 0; j < 16; j++) {
      int l = l0 + j;
      running += vloc[j];
      if (!((cmask[l >> 5] >> (l & 31)) & 1u))
        out[(((size_t)b * Ln + l) * Hn + h) * Dn + d] =
            0.5f * ((float)(l + 1) * vloc[j] + running);
    }
    return;
  }

  // ---- sparse attention over 5 selected rows (VERBATIM R5/R6) ----
  int xcd  = blockIdx.x & 7;
  int rest = blockIdx.x >> 3;     // 0..31
  int chunk = rest & 7;
  int bh    = (rest >> 3) * 8 + xcd;
  int b = bh >> 3, h = bh & 7;
  const float* Qb = Q + (size_t)bh * Ln * Dn;
  const float* Kb = K + (size_t)bh * Ln * Dn;
  const float* Vb = V + (size_t)bh * Ln * Dn;
  int tid = threadIdx.x;

  if (tid < UC * 64) {
    int u = tid >> 6, d = tid & 63;
    int row = Mtop[bh * NTOP + chunk * UC + u];
    if (d == 0) rows_s[u] = row;
    qs[u][d] = Qb[(size_t)row * Dn + d];
    ks[u][d] = Kb[(size_t)row * Dn + d];
    vs[u][d] = Vb[(size_t)row * Dn + d];
  }
  __syncthreads();

  // pass 1: scores[u][l] = 0.0625*(Qsel[u].K[l] + Q[l].Ksel[u]), causal mask l>row
  float acc[UC][4];
#pragma unroll
  for (int u = 0; u < UC; u++)
#pragma unroll
    for (int j = 0; j < 4; j++) acc[u][j] = 0.f;

  for (int tt = 0; tt < 4; tt++) {
    float4 kk[4][4], qq[4][4];    // [j][ts] — 32 loads issued before use
#pragma unroll
    for (int j = 0; j < 4; j++) {
      int l = tid + j * 512;
      const float4* kp = (const float4*)(Kb + (size_t)l * Dn) + tt * 4;
      const float4* qp = (const float4*)(Qb + (size_t)l * Dn) + tt * 4;
#pragma unroll
      for (int ts = 0; ts < 4; ts++) { kk[j][ts] = kp[ts]; qq[j][ts] = qp[ts]; }
    }
#pragma unroll
    for (int ts = 0; ts < 4; ts++) {
      int t = tt * 4 + ts;
#pragma unroll
      for (int u = 0; u < UC; u++) {
        float4 q4 = *(const float4*)(&qs[u][t * 4]);
        float4 k4 = *(const float4*)(&ks[u][t * 4]);
#pragma unroll
        for (int j = 0; j < 4; j++) {
          acc[u][j] += q4.x * kk[j][ts].x + q4.y * kk[j][ts].y
                     + q4.z * kk[j][ts].z + q4.w * kk[j][ts].w
                     + k4.x * qq[j][ts].x + k4.y * qq[j][ts].y
                     + k4.z * qq[j][ts].z + k4.w * qq[j][ts].w;
        }
      }
    }
  }
#pragma unroll
  for (int u = 0; u < UC; u++) {
    int row = rows_s[u];
#pragma unroll
    for (int j = 0; j < 4; j++) {
      int l = tid + j * 512;
      sc[u][l] = (l > row) ? -1e9f : acc[u][j] * 0.0625f;
    }
  }
  __syncthreads();

  // pass 2: softmax per u; wave w handles u=w (waves 0..4)
  int w = tid >> 6, lane = tid & 63;
  if (w < UC) {
    float mx = -INFINITY;
    for (int kq = 0; kq < 32; kq++) mx = fmaxf(mx, sc[w][lane + 64 * kq]);
    for (int off = 32; off; off >>= 1) mx = fmaxf(mx, __shfl_xor(mx, off, 64));
    float sum = 0.f;
    for (int kq = 0; kq < 32; kq++) {
      float e = __expf(sc[w][lane + 64 * kq] - mx);
      sc[w][lane + 64 * kq] = e;
      sum += e;
    }
    for (int off = 32; off; off >>= 1) sum += __shfl_xor(sum, off, 64);
    if (lane == 0) inv_s[w] = 1.0f / sum;
  }
  __syncthreads();

  // pass 3: attn @ V ; wave w owns l in [w*256, w*256+256) for ALL 5 u.
  {
    int quad = lane & 15, lr = lane >> 4;
    int l0w = w * 256;
    const float4* V4 = (const float4*)Vb;
    float4 a[UC];
#pragma unroll
    for (int u = 0; u < UC; u++) a[u] = make_float4(0.f, 0.f, 0.f, 0.f);
    for (int it4 = 0; it4 < 16; it4++) {
      int lb = l0w + lr + it4 * 16;
      float4 v0 = V4[(size_t)(lb)      * 16 + quad];
      float4 v1 = V4[(size_t)(lb + 4)  * 16 + quad];
      float4 v2 = V4[(size_t)(lb + 8)  * 16 + quad];
      float4 v3 = V4[(size_t)(lb + 12) * 16 + quad];
#pragma unroll
      for (int u = 0; u < UC; u++) {
        float s0 = sc[u][lb], s1 = sc[u][lb + 4], s2 = sc[u][lb + 8], s3 = sc[u][lb + 12];
        a[u].x += s0 * v0.x + s1 * v1.x + s2 * v2.x + s3 * v3.x;
        a[u].y += s0 * v0.y + s1 * v1.y + s2 * v2.y + s3 * v3.y;
        a[u].z += s0 * v0.z + s1 * v1.z + s2 * v2.z + s3 * v3.z;
        a[u].w += s0 * v0.w + s1 * v1.w + s2 * v2.w + s3 * v3.w;
      }
    }
#pragma unroll
    for (int u = 0; u < UC; u++) {
#pragma unroll
      for (int off = 16; off < 64; off <<= 1) {
        a[u].x += __shfl_xor(a[u].x, off, 64);
        a[u].y += __shfl_xor(a[u].y, off, 64);
        a[u].z += __shfl_xor(a[u].z, off, 64);
        a[u].w += __shfl_xor(a[u].w, off, 64);
      }
      if (lr == 0) *(float4*)(&redp[w][u][quad * 4]) = a[u];
    }
  }
  __syncthreads();

  if (w < UC) {
    float r = 0.f;
#pragma unroll
    for (int g = 0; g < 8; g++) r += redp[g][w][lane];
    float outv = 0.5f * (vs[w][lane] + r * inv_s[w]);
    int row = rows_s[w];
    out[(((size_t)b * Ln + row) * Hn + h) * Dn + lane] = outv;
  }
}

extern "C" void kernel_launch(void* const* d_in, const int* in_sizes, int n_in,
                              void* d_out, int out_size, void* d_ws, size_t ws_size,
                              hipStream_t stream) {
  const float* Q = (const float*)d_in[0];  // (B,L,H,D) flat == (B,H,L,D) reshape
  const float* K = (const float*)d_in[1];
  const float* V = (const float*)d_in[2];
  float* out = (float*)d_out;
  char* ws = (char*)d_ws;

  float* M       = (float*)(ws + NSAMP * 4);                       // 256 KB
  int*   Mtop    = (int*)(ws + NSAMP * 4 + BHn * Ln * 4);          // 5 KB
  float* partial = (float*)(ws + NSAMP * 4 + BHn * Ln * 4 + BHn * NTOP * 4); // 256 KB

  // Partitionable threefry split of key(42) = (0,42): k2 = tf(key, ctr=(0,1)).
  uint32_t s0 = 0u, s1 = 1u;
  tf2x32(0u, 42u, s0, s1);

  // 3 launches: {vsum || compute_M} -> topk_select -> {sparse_attn || context}
  fused_m_vsum<<<1024 + 8192, 256, 0, stream>>>(Q, K, V, M, partial, s0, s1);
  topk_select<<<BHn, 256, 0, stream>>>(M, Mtop);
  sparse_ctx<<<SPB + 512, 512, 0, stream>>>(Q, K, V, Mtop, partial, out);
}

// Round 8
// 178.213 us; speedup vs baseline: 2.3272x; 1.0006x over previous
//
#include <hip/hip_runtime.h>
#include <stdint.h>
#include <math.h>

// Problem constants (B,L,H,D fixed by setup_inputs)
#define Bn 4
#define Ln 2048
#define Hn 8
#define Dn 64
#define BHn (Bn*Hn)
#define NTOP 40   // FACTOR * ceil(log(2048)) = 5*8
#define SK   40
#define NSAMP (Ln*SK)        // 81920

// ---------------- Threefry-2x32 (exact JAX replication) ----------------
__host__ __device__ inline uint32_t rotl32(uint32_t x, int r) {
  return (x << r) | (x >> (32 - r));
}

__host__ __device__ inline void tf2x32(uint32_t k0, uint32_t k1,
                                       uint32_t& x0, uint32_t& x1) {
  const uint32_t ks2 = k0 ^ k1 ^ 0x1BD11BDAu;
  const int RA[4] = {13, 15, 26, 6};
  const int RB[4] = {17, 29, 16, 24};
  x0 += k0; x1 += k1;
  for (int i = 0; i < 4; i++) { x0 += x1; x1 = rotl32(x1, RA[i]); x1 ^= x0; }
  x0 += k1;  x1 += ks2 + 1u;
  for (int i = 0; i < 4; i++) { x0 += x1; x1 = rotl32(x1, RB[i]); x1 ^= x0; }
  x0 += ks2; x1 += k0 + 2u;
  for (int i = 0; i < 4; i++) { x0 += x1; x1 = rotl32(x1, RA[i]); x1 ^= x0; }
  x0 += k0;  x1 += k1 + 3u;
  for (int i = 0; i < 4; i++) { x0 += x1; x1 = rotl32(x1, RB[i]); x1 ^= x0; }
  x0 += k1;  x1 += ks2 + 4u;
  for (int i = 0; i < 4; i++) { x0 += x1; x1 = rotl32(x1, RA[i]); x1 ^= x0; }
  x0 += ks2; x1 += k0 + 5u;
}

// jax_threefry_partitionable=True: elem n -> ctr (0, n); draw = out0 ^ out1
__device__ inline int draw2048(uint32_t k0, uint32_t k1, uint32_t n) {
  uint32_t a = 0u, b = n;
  tf2x32(k0, k1, a, b);
  return (int)((a ^ b) & (Ln - 1));
}

// ---------------- DPP 16-lane sum reduce (VALU pipe, zero DS ops) ----------------
template<int CTRL>
__device__ __forceinline__ float dpp_add(float x) {
  int y = __builtin_amdgcn_update_dpp(0, __float_as_int(x), CTRL, 0xF, 0xF, true);
  return x + __int_as_float(y);
}
__device__ __forceinline__ float red16(float d) {
  d = dpp_add<0xB1>(d);   // quad_perm [1,0,3,2]  (xor 1)
  d = dpp_add<0x4E>(d);   // quad_perm [2,3,0,1]  (xor 2)
  d = dpp_add<0x141>(d);  // row_half_mirror      (pairs across 8-halves)
  d = dpp_add<0x140>(d);  // row_mirror           (pairs across 16-row)
  return d;
}

// ---------------- fused launch 1: vsum_partial (blocks 0..1023) +
//                  compute_M v5 (blocks 1024..9215) ----------------
// v5: R7 showed the serial-chain halving (v4) bought ~nothing -> the gather is
// MLP/issue-limited, not chain-limited. v5 pre-issues ALL 20 of a half-wave's
// sample loads (kf[5][4], static indexing, ~80 load VGPRs) before the first
// reduce: 20 global_load_dwordx4 back-to-back, 2.5x the loads in flight.
// Threefry draws, per-sample dot/red16, 20+20 half split: bit-identical to v4.
// Tripwire: launch-1 WRITE_SIZE ~1 MB; a balloon = spill -> revert.
__global__ __launch_bounds__(256) void fused_m_vsum(const float* __restrict__ Q,
                                                    const float* __restrict__ K,
                                                    const float* __restrict__ V,
                                                    float* __restrict__ M,
                                                    float* __restrict__ partial,
                                                    uint32_t k0, uint32_t k1) {
  __shared__ alignas(16) int sidx[8][40];    // compute_M path (1.25 KB)
  __shared__ float red[4][64];               // vsum path (1 KB)

  if (blockIdx.x < 1024) {
    // ---- vsum_partial: per-tile (64 l) V sums ----
    int bid  = blockIdx.x;
    int tile = bid & 31;
    int bh   = bid >> 5;
    int d = threadIdx.x & 63;
    int g = threadIdx.x >> 6;
    const float* Vb = V + (size_t)bh * Ln * Dn;
    int l0 = tile * 64 + g * 16;
    float s = 0.f;
    for (int j = 0; j < 16; j++) s += Vb[(size_t)(l0 + j) * Dn + d];
    red[g][d] = s;
    __syncthreads();
    if (g == 0)
      partial[((size_t)bh * 32 + tile) * 64 + d] =
          red[0][d] + red[1][d] + red[2][d] + red[3][d];
    return;
  }

  int cmb = blockIdx.x - 1024;        // 0..8191; 1024%8==0 keeps xcd mapping
  int xcd = cmb & 7;
  int idx = cmb >> 3;                 // 0..1023
  int bh  = (idx & 3) * 8 + xcd;      // {xcd, xcd+8, xcd+16, xcd+24}
  int seg = idx >> 2;                 // 0..255
  int tid = threadIdx.x;
  int q   = tid >> 5;                 // query slot in wg: 0..7
  int h   = tid & 31;                 // lane within half-wave
  int j   = h & 15;                   // float4 slot within row
  int p   = h >> 4;                   // sample-half: samples [p*20, p*20+20)
  int i   = seg * 8 + q;              // query index

  // index gen: thread (q, l=h) draws sample l; l<8 also draws 32+l
  {
    uint32_t n0 = (uint32_t)(i * SK);
    sidx[q][h] = draw2048(k0, k1, n0 + h);
    if (h < 8) sidx[q][32 + h] = draw2048(k0, k1, n0 + 32 + h);
  }

  const float* Qb = Q + ((size_t)bh * Ln + i) * Dn;
  float4 qf = ((const float4*)Qb)[j];
  __syncthreads();

  // this half's 20 indices (5 int4 groups; p*20*4B = 80B, 16B-aligned)
  int4 I[5];
#pragma unroll
  for (int t = 0; t < 5; t++) I[t] = *(const int4*)&sidx[q][p * 20 + t * 4];

  const float* Kb = K + (size_t)bh * Ln * Dn;

  // pre-issue ALL 20 gather loads (full MLP), then reduce
  float4 kf[5][4];
#pragma unroll
  for (int t = 0; t < 5; t++) {
    int ls[4] = {I[t].x, I[t].y, I[t].z, I[t].w};
#pragma unroll
    for (int c = 0; c < 4; c++)
      kf[t][c] = ((const float4*)(Kb + (size_t)ls[c] * Dn))[j];
  }

  float mx = -INFINITY, sm = 0.f;
#pragma unroll
  for (int t = 0; t < 5; t++) {
#pragma unroll
    for (int c = 0; c < 4; c++) {
      float d = qf.x * kf[t][c].x + qf.y * kf[t][c].y
              + qf.z * kf[t][c].z + qf.w * kf[t][c].w;
      d = red16(d);                    // full 64-elem dot in every lane
      mx = fmaxf(mx, d);
      sm += d;
    }
  }
  // merge the two 20-sample halves (stays within the 32-lane half-wave)
  mx = fmaxf(mx, __shfl_xor(mx, 16, 64));
  sm += __shfl_xor(sm, 16, 64);
  if (h == 0)
    M[(size_t)bh * Ln + i] = mx - sm * (1.0f / (float)Ln);
}

// ---------------- launch 2: unordered exact top-40 via bisection select ----------------
// (proven R6/R7)
__global__ __launch_bounds__(256) void topk_select(const float* __restrict__ M,
                                                   int* __restrict__ Mtop) {
  int bh = blockIdx.x;
  int tid = threadIdx.x;
  const float* m = M + (size_t)bh * Ln;

  // 8 contiguous values per thread (2x dwordx4), monotonic keys
  uint32_t k[8]; int li[8];
  float4 va = ((const float4*)m)[tid * 2];
  float4 vb = ((const float4*)m)[tid * 2 + 1];
  float vals[8] = {va.x, va.y, va.z, va.w, vb.x, vb.y, vb.z, vb.w};
#pragma unroll
  for (int j = 0; j < 8; j++) {
    uint32_t u = __float_as_uint(vals[j]);
    k[j] = (u & 0x80000000u) ? ~u : (u | 0x80000000u);
    li[j] = tid * 8 + j;
  }

  __shared__ int cnts[32];
  __shared__ int cA, outc, eqn2;
  __shared__ int eqbuf[2048];
  if (tid < 32) cnts[tid] = 0;
  if (tid == 0) { cA = 0; outc = 0; eqn2 = 0; }
  __syncthreads();

  // find K40 = max T with count(key >= T) >= NTOP
  uint32_t lo = 0u, hi = 0xFFFFFFFFu;
  for (int it = 0; it < 32; ++it) {
    if (lo >= hi) break;                       // uniform across block
    uint32_t mid = lo + ((hi - lo) >> 1) + 1u; // in (lo, hi], no overflow
    int cw = 0;
#pragma unroll
    for (int j = 0; j < 8; j++)
      cw += __popcll(__ballot(k[j] >= mid));
    if ((tid & 63) == 0) atomicAdd(&cnts[it], cw);
    __syncthreads();
    int total = cnts[it];
    if (total >= NTOP) lo = mid; else hi = mid - 1u;
  }
  uint32_t K40 = lo;

  // count strictly-above
  {
    int cw = 0;
#pragma unroll
    for (int j = 0; j < 8; j++)
      cw += __popcll(__ballot(k[j] > K40));
    if ((tid & 63) == 0) atomicAdd(&cA, cw);
  }
  __syncthreads();

  // compact: strictly-greater (any order), ties into eqbuf
#pragma unroll
  for (int j = 0; j < 8; j++) {
    if (k[j] > K40) {
      int p = atomicAdd(&outc, 1);
      Mtop[bh * NTOP + p] = li[j];
    } else if (k[j] == K40) {
      int p = atomicAdd(&eqn2, 1);
      eqbuf[p] = li[j];
    }
  }
  __syncthreads();

  if (tid == 0) {
    int need = NTOP - cA;        // >= 1 by construction of K40
    int n = eqn2;
    for (int s = 0; s < need; s++) {   // typically need==1, n==1
      int best = 0x7fffffff, bi = 0;
      for (int t = 0; t < n; t++)
        if (eqbuf[t] < best) { best = eqbuf[t]; bi = t; }
      Mtop[bh * NTOP + cA + s] = best;
      eqbuf[bi] = 0x7fffffff;
    }
  }
}

// ---------------- launch 3: sparse attention (blocks 0..255, VERBATIM proven)
//                  + context_write (blocks 256..511, 256-l tiles) ----------------
// R7: sparse_ctx 61.5 us vs sparse-alone <=56 -- 57.9 KB LDS caps 2 blocks/CU,
// so the old 512 ctx blocks needed a second scheduling round behind sparse.
// v2 ctx: 256 blocks (grid 512 = exactly 2/CU, ONE resident round), each block
// covers 256 l's via two sequential 128-l passes; vloc stays 16 regs. Sparse
// path untouched. Tripwire: WRITE_SIZE ~21 MB; >>25 MB means spill returned.
#define UC 5
#define SPB 256
__global__ __launch_bounds__(512, 2) void sparse_ctx(const float* __restrict__ Q,
                                                     const float* __restrict__ K,
                                                     const float* __restrict__ V,
                                                     const int* __restrict__ Mtop,
                                                     const float* __restrict__ partial,
                                                     float* __restrict__ out) {
  __shared__ alignas(16) float sc[UC][Ln];           // 40 KB scores->probs
  __shared__ alignas(16) float qs[UC][Dn];
  __shared__ alignas(16) float ks[UC][Dn];
  __shared__ float vs[UC][Dn];
  __shared__ alignas(16) float redp[8][UC][64];      // 10 KB partial attn@V
  __shared__ int   rows_s[UC];
  __shared__ float inv_s[UC];
  __shared__ alignas(16) float credR[8][64];         // ctx path (2 KB)
  __shared__ uint32_t cmask[64];                     // ctx path: selected-row bits

  if (blockIdx.x >= SPB) {
    // ---- context_write: prefix + cumsum + transposed write, skip selected ----
    int bid = blockIdx.x - SPB;      // 0..255
    int bh  = bid >> 3;              // 0..31
    int T   = bid & 7;               // 256-l tile
    int b = bh >> 3, h = bh & 7;
    int tid = threadIdx.x, d = tid & 63, g = tid >> 6;   // g 0..7
    if (tid < 64) cmask[tid] = 0u;
    __syncthreads();
    if (tid < NTOP) {
      int r = Mtop[bh * NTOP + tid];
      atomicOr(&cmask[r >> 5], 1u << (r & 31));
    }
    float p = 0.f;
    for (int t = g; t < 4 * T; t += 8)
      p += partial[((size_t)bh * 32 + t) * 64 + d];
    credR[g][d] = p;
    __syncthreads();                 // also fences cmask population
    float prefix = 0.f;
#pragma unroll
    for (int gg = 0; gg < 8; gg++) prefix += credR[gg][d];
    __syncthreads();
    const float* Vb = V + (size_t)bh * Ln * Dn;
#pragma unroll
    for (int pass = 0; pass < 2; pass++) {
      int l0 = T * 256 + pass * 128 + g * 16;
      float vloc[16]; float s = 0.f;
      for (int j = 0; j < 16; j++) {
        vloc[j] = Vb[(size_t)(l0 + j) * Dn + d];
        s += vloc[j];
      }
      credR[g][d] = s;
      __syncthreads();
      float running = prefix;
      for (int gg = 0; gg < g; gg++) running += credR[gg][d];
      for (int j = 0; j < 16; j++) {
        int l = l0 + j;
        running += vloc[j];
        if (!((cmask[l >> 5] >> (l & 31)) & 1u))
          out[(((size_t)b * Ln + l) * Hn + h) * Dn + d] =
              0.5f * ((float)(l + 1) * vloc[j] + running);
      }
      if (pass == 0) {
        float all8 = 0.f;
#pragma unroll
        for (int gg = 0; gg < 8; gg++) all8 += credR[gg][d];
        prefix += all8;
        __syncthreads();             // credR reused next pass
      }
    }
    return;
  }

  // ---- sparse attention over 5 selected rows (VERBATIM R5/R6/R7) ----
  int xcd  = blockIdx.x & 7;
  int rest = blockIdx.x >> 3;     // 0..31
  int chunk = rest & 7;
  int bh    = (rest >> 3) * 8 + xcd;
  int b = bh >> 3, h = bh & 7;
  const float* Qb = Q + (size_t)bh * Ln * Dn;
  const float* Kb = K + (size_t)bh * Ln * Dn;
  const float* Vb = V + (size_t)bh * Ln * Dn;
  int tid = threadIdx.x;

  if (tid < UC * 64) {
    int u = tid >> 6, d = tid & 63;
    int row = Mtop[bh * NTOP + chunk * UC + u];
    if (d == 0) rows_s[u] = row;
    qs[u][d] = Qb[(size_t)row * Dn + d];
    ks[u][d] = Kb[(size_t)row * Dn + d];
    vs[u][d] = Vb[(size_t)row * Dn + d];
  }
  __syncthreads();

  // pass 1: scores[u][l] = 0.0625*(Qsel[u].K[l] + Q[l].Ksel[u]), causal mask l>row
  float acc[UC][4];
#pragma unroll
  for (int u = 0; u < UC; u++)
#pragma unroll
    for (int j = 0; j < 4; j++) acc[u][j] = 0.f;

  for (int tt = 0; tt < 4; tt++) {
    float4 kk[4][4], qq[4][4];    // [j][ts] — 32 loads issued before use
#pragma unroll
    for (int j = 0; j < 4; j++) {
      int l = tid + j * 512;
      const float4* kp = (const float4*)(Kb + (size_t)l * Dn) + tt * 4;
      const float4* qp = (const float4*)(Qb + (size_t)l * Dn) + tt * 4;
#pragma unroll
      for (int ts = 0; ts < 4; ts++) { kk[j][ts] = kp[ts]; qq[j][ts] = qp[ts]; }
    }
#pragma unroll
    for (int ts = 0; ts < 4; ts++) {
      int t = tt * 4 + ts;
#pragma unroll
      for (int u = 0; u < UC; u++) {
        float4 q4 = *(const float4*)(&qs[u][t * 4]);
        float4 k4 = *(const float4*)(&ks[u][t * 4]);
#pragma unroll
        for (int j = 0; j < 4; j++) {
          acc[u][j] += q4.x * kk[j][ts].x + q4.y * kk[j][ts].y
                     + q4.z * kk[j][ts].z + q4.w * kk[j][ts].w
                     + k4.x * qq[j][ts].x + k4.y * qq[j][ts].y
                     + k4.z * qq[j][ts].z + k4.w * qq[j][ts].w;
        }
      }
    }
  }
#pragma unroll
  for (int u = 0; u < UC; u++) {
    int row = rows_s[u];
#pragma unroll
    for (int j = 0; j < 4; j++) {
      int l = tid + j * 512;
      sc[u][l] = (l > row) ? -1e9f : acc[u][j] * 0.0625f;
    }
  }
  __syncthreads();

  // pass 2: softmax per u; wave w handles u=w (waves 0..4)
  int w = tid >> 6, lane = tid & 63;
  if (w < UC) {
    float mx = -INFINITY;
    for (int kq = 0; kq < 32; kq++) mx = fmaxf(mx, sc[w][lane + 64 * kq]);
    for (int off = 32; off; off >>= 1) mx = fmaxf(mx, __shfl_xor(mx, off, 64));
    float sum = 0.f;
    for (int kq = 0; kq < 32; kq++) {
      float e = __expf(sc[w][lane + 64 * kq] - mx);
      sc[w][lane + 64 * kq] = e;
      sum += e;
    }
    for (int off = 32; off; off >>= 1) sum += __shfl_xor(sum, off, 64);
    if (lane == 0) inv_s[w] = 1.0f / sum;
  }
  __syncthreads();

  // pass 3: attn @ V ; wave w owns l in [w*256, w*256+256) for ALL 5 u.
  {
    int quad = lane & 15, lr = lane >> 4;
    int l0w = w * 256;
    const float4* V4 = (const float4*)Vb;
    float4 a[UC];
#pragma unroll
    for (int u = 0; u < UC; u++) a[u] = make_float4(0.f, 0.f, 0.f, 0.f);
    for (int it4 = 0; it4 < 16; it4++) {
      int lb = l0w + lr + it4 * 16;
      float4 v0 = V4[(size_t)(lb)      * 16 + quad];
      float4 v1 = V4[(size_t)(lb + 4)  * 16 + quad];
      float4 v2 = V4[(size_t)(lb + 8)  * 16 + quad];
      float4 v3 = V4[(size_t)(lb + 12) * 16 + quad];
#pragma unroll
      for (int u = 0; u < UC; u++) {
        float s0 = sc[u][lb], s1 = sc[u][lb + 4], s2 = sc[u][lb + 8], s3 = sc[u][lb + 12];
        a[u].x += s0 * v0.x + s1 * v1.x + s2 * v2.x + s3 * v3.x;
        a[u].y += s0 * v0.y + s1 * v1.y + s2 * v2.y + s3 * v3.y;
        a[u].z += s0 * v0.z + s1 * v1.z + s2 * v2.z + s3 * v3.z;
        a[u].w += s0 * v0.w + s1 * v1.w + s2 * v2.w + s3 * v3.w;
      }
    }
#pragma unroll
    for (int u = 0; u < UC; u++) {
#pragma unroll
      for (int off = 16; off < 64; off <<= 1) {
        a[u].x += __shfl_xor(a[u].x, off, 64);
        a[u].y += __shfl_xor(a[u].y, off, 64);
        a[u].z += __shfl_xor(a[u].z, off, 64);
        a[u].w += __shfl_xor(a[u].w, off, 64);
      }
      if (lr == 0) *(float4*)(&redp[w][u][quad * 4]) = a[u];
    }
  }
  __syncthreads();

  if (w < UC) {
    float r = 0.f;
#pragma unroll
    for (int g = 0; g < 8; g++) r += redp[g][w][lane];
    float outv = 0.5f * (vs[w][lane] + r * inv_s[w]);
    int row = rows_s[w];
    out[(((size_t)b * Ln + row) * Hn + h) * Dn + lane] = outv;
  }
}

extern "C" void kernel_launch(void* const* d_in, const int* in_sizes, int n_in,
                              void* d_out, int out_size, void* d_ws, size_t ws_size,
                              hipStream_t stream) {
  const float* Q = (const float*)d_in[0];  // (B,L,H,D) flat == (B,H,L,D) reshape
  const float* K = (const float*)d_in[1];
  const float* V = (const float*)d_in[2];
  float* out = (float*)d_out;
  char* ws = (char*)d_ws;

  float* M       = (float*)(ws + NSAMP * 4);                       // 256 KB
  int*   Mtop    = (int*)(ws + NSAMP * 4 + BHn * Ln * 4);          // 5 KB
  float* partial = (float*)(ws + NSAMP * 4 + BHn * Ln * 4 + BHn * NTOP * 4); // 256 KB

  // Partitionable threefry split of key(42) = (0,42): k2 = tf(key, ctr=(0,1)).
  uint32_t s0 = 0u, s1 = 1u;
  tf2x32(0u, 42u, s0, s1);

  // 3 launches: {vsum || compute_M} -> topk_select -> {sparse_attn || context}
  fused_m_vsum<<<1024 + 8192, 256, 0, stream>>>(Q, K, V, M, partial, s0, s1);
  topk_select<<<BHn, 256, 0, stream>>>(M, Mtop);
  sparse_ctx<<<SPB + 256, 512, 0, stream>>>(Q, K, V, Mtop, partial, out);
}